// Round 5
// baseline (210.421 us; speedup 1.0000x reference)
//
#include <hip/hip_runtime.h>

#define NB 8
#define NNODE 2048
#define NE 32768
#define NG 4
#define NH 64
#define NMLP 128

// ---------------- persistent device scratch ----------------------------------
__device__ __align__(16) float g_fold[2*NG*12*64];   // folded layer-1 weights
__device__ __align__(16) float g_bc[2*NG*64];        // folded layer-1 bias
__device__ __align__(16) float g_q1[64];             // se_w @ nu1_w[0:64]
__device__ __align__(16) float g_b1f[64];            // se_b @ nu1_w[0:64] + nu1_b
__device__ __align__(16) float g_em[(size_t)NE*NB*64]; // gated edge messages (paths combined)
__device__ __align__(16) float g_msg[NB*NNODE*64];   // per-node reduced messages
__device__ __align__(16) float g_psum[NB*NMLP];
__device__ int g_elist[NG*NE];
__device__ int g_ecnt[NG];
__device__ int g_ncnt[NNODE];
__device__ int g_noff[NNODE];
__device__ int g_cur[NNODE];
__device__ int g_csr[NE];

__device__ __forceinline__ float lrelu(float x){ return fmaxf(x, 0.01f*x); }

// ---------------- init: zero the small accumulators only ---------------------
__global__ void k_init() {
  int i = blockIdx.x*blockDim.x + threadIdx.x;   // 2048 threads
  if (i < NNODE) g_ncnt[i] = 0;
  if (i < NB*NMLP) g_psum[i] = 0.f;
  if (i < NG) g_ecnt[i] = 0;
}

// ---------------- bucket edges by group (wave-aggregated atomics) ------------
// + count receivers (2048 bins, low contention, raw atomics fine)
__global__ void k_bucket(const int* __restrict__ uc, const int* __restrict__ idx2) {
  int e = blockIdx.x*blockDim.x + threadIdx.x;
  int lane = threadIdx.x & 63;
  int g = (e < NE) ? uc[e] : -1;
  #pragma unroll
  for (int gg = 0; gg < NG; gg++){
    bool mine = (g == gg);
    unsigned long long mask = __ballot(mine);
    if (mine){
      int leader = __ffsll((unsigned long long)mask) - 1;
      int r = __popcll(mask & ((1ULL << lane) - 1ULL));
      int base = 0;
      if (lane == leader) base = atomicAdd(&g_ecnt[gg], (int)__popcll(mask));
      base = __shfl(base, leader, 64);
      g_elist[gg*NE + base + r] = e;
    }
  }
  if (e < NE) atomicAdd(&g_ncnt[idx2[e]], 1);
}

// ---------------- exclusive scan of node counts (1 wave) ---------------------
__global__ void k_scan() {
  int lane = threadIdx.x;              // 64 lanes, 32 nodes each
  int base = lane * 32;
  int loc[32];
  int s = 0;
  #pragma unroll
  for (int i=0;i<32;i++){ loc[i] = s; s += g_ncnt[base+i]; }
  int tot = s;
  #pragma unroll
  for (int d=1; d<64; d<<=1){
    int v = __shfl_up(tot, d, 64);
    if (lane >= d) tot += v;
  }
  int excl = tot - s;
  #pragma unroll
  for (int i=0;i<32;i++){ int o = excl + loc[i]; g_noff[base+i] = o; g_cur[base+i] = o; }
}

// ---------------- place edges into CSR by receiver ----------------------------
__global__ void k_place(const int* __restrict__ idx2) {
  int e = blockIdx.x*blockDim.x + threadIdx.x;
  if (e < NE) {
    int n = idx2[e];
    int pos = atomicAdd(&g_cur[n], 1);
    g_csr[pos] = e;
  }
}

// ---------------- fold rank-1 / rank-10 inputs through layer-1 weights -------
__global__ void k_fold(const float* __restrict__ se_w, const float* __restrict__ se_b,
                       const float* __restrict__ ee_w, const float* __restrict__ ee_b,
                       const float* __restrict__ m1a_w, const float* __restrict__ m1a_b,
                       const float* __restrict__ m2a_w, const float* __restrict__ m2a_b,
                       const float* __restrict__ nu1_w, const float* __restrict__ nu1_b) {
  int t = threadIdx.x;
  if (t < 512) {
    int p = t>>8, g = (t>>6)&3, j = t&63;
    const float* ma = (p ? m2a_w : m1a_w) + g*160*64;
    const float* mb = (p ? m2a_b : m1a_b) + g*64;
    float* W = g_fold + (p*NG+g)*12*64;
    float a0=0.f, a1=0.f, bc=0.f;
    for (int k=0;k<64;k++){
      float sw = se_w[k], sb = se_b[k];
      float w0 = ma[k*64+j], w1 = ma[(64+k)*64+j];
      a0 += sw*w0; a1 += sw*w1; bc += sb*(w0+w1);
    }
    W[0*64+j]=a0; W[1*64+j]=a1;
    for (int c=0;c<10;c++){
      float pc=0.f;
      for (int u=0;u<32;u++) pc += ee_w[c*32+u]*ma[(128+u)*64+j];
      W[(2+c)*64+j]=pc;
    }
    for (int u=0;u<32;u++) bc += ee_b[u]*ma[(128+u)*64+j];
    g_bc[(p*NG+g)*64+j] = bc + mb[j];
  } else if (t < 576) {
    int j = t - 512;
    float q=0.f, bf=0.f;
    for (int k=0;k<64;k++){ float w = nu1_w[k*64+j]; q += se_w[k]*w; bf += se_b[k]*w; }
    g_q1[j]=q; g_b1f[j]=bf + nu1_b[j];
  }
}

// ---------------- edge kernel: 8 edges x 8 batches = 64 rows per block -------
// folded layer1 -> LDS (XOR swizzle) -> 64x64 GEMM (4x8/thread) -> leaky
// -> attention gate -> combine both paths in regs -> ONE dense store to g_em
__global__ __launch_bounds__(128) void k_edge(
    const float* __restrict__ sites, const float* __restrict__ bonds,
    const int* __restrict__ idx1, const int* __restrict__ idx2,
    const float* __restrict__ m1b_w, const float* __restrict__ m1b_b,
    const float* __restrict__ m2b_w, const float* __restrict__ m2b_b,
    const float* __restrict__ att1_w, const float* __restrict__ att1_b,
    const float* __restrict__ att2_w, const float* __restrict__ att2_b) {
  int g = blockIdx.y;
  int cnt = g_ecnt[g];
  int e8 = blockIdx.x * 8;
  if (e8 >= cnt) return;

  __shared__ __align__(16) float hA[64*64];
  __shared__ __align__(16) float W2s[64*64];
  __shared__ __align__(16) float fls[64*12];
  __shared__ __align__(16) float attws[2*64];
  __shared__ float attp[64];
  __shared__ int sbase[64];

  int t = threadIdx.x;
  int lane = t & 63;
  int wv = t >> 6;

  // folded layer-1 weights in registers
  float w1r[2][12], bcr[2];
  #pragma unroll
  for (int p=0;p<2;p++){
    const float* W = g_fold + (p*NG+g)*12*64;
    #pragma unroll
    for (int r=0;r<12;r++) w1r[p][r] = W[r*64+lane];
    bcr[p] = g_bc[(p*NG+g)*64+lane];
  }
  if (t < 64) attws[t] = att1_w[t];
  else        attws[t] = att2_w[t-64];

  if (t < 64) {
    int r = t, ei = r>>3, b = r&7;
    int eslot = e8 + ei;
    bool valid = eslot < cnt;
    int e = g_elist[g*NE + (valid ? eslot : e8)];
    int i1 = idx1[e], i2 = idx2[e];
    float d = bonds[b*NE + e];
    fls[r*12+0] = sites[b*NNODE + i1];
    fls[r*12+1] = sites[b*NNODE + i2];
    sbase[r] = valid ? (e*NB + b)*64 : -1;
    #pragma unroll
    for (int c=0;c<10;c++){
      float dd = d - c*(10.f/9.f);
      fls[r*12+2+c] = __expf(-dd*dd);
    }
  }

  int m0 = (t&15)*4, n0 = (t>>4)*8;
  int swz = ((m0>>3)&7)<<2;
  float out0[4][8];

  #pragma unroll
  for (int p=0;p<2;p++){
    const float* W2g = (p ? m2b_w : m1b_w) + g*64*64;
    const float* b2g = (p ? m2b_b : m1b_b) + g*64;
    float attb = p ? att2_b[0] : att1_b[0];

    __syncthreads();   // previous-phase readers done; fls/sbase ready (p=0)
    #pragma unroll
    for (int i=0;i<8;i++) ((float4*)W2s)[i*128 + t] = ((const float4*)W2g)[i*128 + t];
    if (t < 64) attp[t] = 0.f;

    // layer 1: lane = output column; each wave covers 32 rows
    for (int m = wv*32; m < wv*32 + 32; m++){
      const float4 fa = *(const float4*)&fls[m*12];
      const float4 fb = *(const float4*)&fls[m*12+4];
      const float4 fc = *(const float4*)&fls[m*12+8];
      float hv = bcr[p]
        + fa.x*w1r[p][0] + fa.y*w1r[p][1] + fa.z*w1r[p][2] + fa.w*w1r[p][3]
        + fb.x*w1r[p][4] + fb.y*w1r[p][5] + fb.z*w1r[p][6] + fb.w*w1r[p][7]
        + fc.x*w1r[p][8] + fc.y*w1r[p][9] + fc.z*w1r[p][10] + fc.w*w1r[p][11];
      hA[m*64 + (lane ^ (((m>>3)&7)<<2))] = lrelu(hv);
    }
    __syncthreads();

    // GEMM2: 64x64 @ 64x64, 4x8 per thread
    float acc[4][8];
    {
      float4 u = *(const float4*)&b2g[n0];
      float4 v = *(const float4*)&b2g[n0+4];
      #pragma unroll
      for (int mm=0;mm<4;mm++){
        acc[mm][0]=u.x; acc[mm][1]=u.y; acc[mm][2]=u.z; acc[mm][3]=u.w;
        acc[mm][4]=v.x; acc[mm][5]=v.y; acc[mm][6]=v.z; acc[mm][7]=v.w;
      }
    }
    for (int kk0=0; kk0<64; kk0+=4){
      int kkE = kk0 ^ swz;
      float br[4][8];
      #pragma unroll
      for (int i=0;i<4;i++){
        float4 u = *(const float4*)&W2s[(kk0+i)*64 + n0];
        float4 v = *(const float4*)&W2s[(kk0+i)*64 + n0+4];
        br[i][0]=u.x; br[i][1]=u.y; br[i][2]=u.z; br[i][3]=u.w;
        br[i][4]=v.x; br[i][5]=v.y; br[i][6]=v.z; br[i][7]=v.w;
      }
      #pragma unroll
      for (int mm=0;mm<4;mm++){
        float4 a = *(const float4*)&hA[(m0+mm)*64 + kkE];
        #pragma unroll
        for (int nn=0;nn<8;nn++)
          acc[mm][nn] += a.x*br[0][nn] + a.y*br[1][nn] + a.z*br[2][nn] + a.w*br[3][nn];
      }
    }
    // leaky + attention row-dot partials
    #pragma unroll
    for (int mm=0;mm<4;mm++){
      float pa = 0.f;
      #pragma unroll
      for (int nn=0;nn<8;nn++){
        float o = lrelu(acc[mm][nn]);
        acc[mm][nn] = o;
        pa += o * attws[p*64 + n0 + nn];
      }
      atomicAdd(&attp[m0+mm], pa);
    }
    __syncthreads();

    // gate; path0 -> regs, path1 -> combine + single dense store
    #pragma unroll
    for (int mm=0;mm<4;mm++){
      float z = attp[m0+mm] + attb;
      float sg = 1.f/(1.f + __expf(-z));
      if (p == 0){
        #pragma unroll
        for (int nn=0;nn<8;nn++) out0[mm][nn] = sg*acc[mm][nn];
      } else {
        int sb = sbase[m0+mm];
        if (sb >= 0){
          float4 u, v;
          u.x = out0[mm][0] + sg*acc[mm][0];
          u.y = out0[mm][1] + sg*acc[mm][1];
          u.z = out0[mm][2] + sg*acc[mm][2];
          u.w = out0[mm][3] + sg*acc[mm][3];
          v.x = out0[mm][4] + sg*acc[mm][4];
          v.y = out0[mm][5] + sg*acc[mm][5];
          v.z = out0[mm][6] + sg*acc[mm][6];
          v.w = out0[mm][7] + sg*acc[mm][7];
          *(float4*)&g_em[sb + n0]     = u;
          *(float4*)&g_em[sb + n0 + 4] = v;
        }
      }
    }
  }
}

// ---------------- gather: CSR segment-reduce, no atomics ---------------------
__global__ __launch_bounds__(256) void k_gather() {
  int w = blockIdx.x*4 + (threadIdx.x >> 6);
  int lane = threadIdx.x & 63;
  int n = w >> 3, b = w & 7;
  int off = g_noff[n], deg = g_ncnt[n];
  float s0 = 0.f, s1 = 0.f;
  int i = 0;
  for (; i+2 <= deg; i += 2){
    int e0 = g_csr[off+i], e1 = g_csr[off+i+1];
    s0 += g_em[(size_t)(e0*NB + b)*64 + lane];
    s1 += g_em[(size_t)(e1*NB + b)*64 + lane];
  }
  if (i < deg){
    int e0 = g_csr[off+i];
    s0 += g_em[(size_t)(e0*NB + b)*64 + lane];
  }
  g_msg[(b*NNODE + n)*64 + lane] = s0 + s1;
}

// ---------------- node kernel: 64 nodes/block, 3 chained GEMMs ---------------
__global__ __launch_bounds__(256) void k_node(
    const float* __restrict__ sites,
    const float* __restrict__ se_w, const float* __restrict__ se_b,
    const float* __restrict__ nu1_w, const float* __restrict__ nu2_w,
    const float* __restrict__ nu2_b,
    const float* __restrict__ p1_w, const float* __restrict__ p1_b) {
  __shared__ __align__(16) float A0[64*64];
  __shared__ __align__(16) float A1[64*64];
  __shared__ __align__(16) float Wb[64*128];
  __shared__ float xs[64];
  __shared__ float colsum[128];
  int t = threadIdx.x;
  int b = blockIdx.x >> 5;
  int nbase = (blockIdx.x & 31) * 64;

  #pragma unroll
  for (int i=0;i<4;i++){
    int idx4 = i*256 + t;
    int row = idx4 >> 4;
    int kb = (idx4 & 15) * 4;
    float4 v = *(const float4*)&g_msg[(b*NNODE + nbase + row)*64 + kb];
    *(float4*)&A0[row*64 + (kb ^ (((row>>3)&7)<<2))] = v;
  }
  if (t < 64) xs[t] = sites[b*NNODE + nbase + t];
  if (t < 128) colsum[t] = 0.f;
  #pragma unroll
  for (int i=0;i<4;i++) ((float4*)Wb)[i*256 + t] = ((const float4*)(nu1_w + 64*64))[i*256 + t];
  __syncthreads();

  int m0 = (t&15)*4;
  int swz = ((m0>>3)&7)<<2;
  int n0 = (t>>4)*4;
  float xr[4];
  #pragma unroll
  for (int mm=0;mm<4;mm++) xr[mm] = xs[m0+mm];

  // GEMM1: h1 = leaky(x*q1 + msg @ nu1_w[64:] + b1f)
  float acc[4][4];
  {
    float4 q  = *(const float4*)&g_q1[n0];
    float4 bf = *(const float4*)&g_b1f[n0];
    #pragma unroll
    for (int mm=0;mm<4;mm++){
      acc[mm][0] = xr[mm]*q.x + bf.x;
      acc[mm][1] = xr[mm]*q.y + bf.y;
      acc[mm][2] = xr[mm]*q.z + bf.z;
      acc[mm][3] = xr[mm]*q.w + bf.w;
    }
  }
  for (int kk0=0;kk0<64;kk0+=4){
    int kkE = kk0 ^ swz;
    float br[4][4];
    #pragma unroll
    for (int i=0;i<4;i++){
      float4 u = *(const float4*)&Wb[(kk0+i)*64 + n0];
      br[i][0]=u.x; br[i][1]=u.y; br[i][2]=u.z; br[i][3]=u.w;
    }
    #pragma unroll
    for (int mm=0;mm<4;mm++){
      float4 a = *(const float4*)&A0[(m0+mm)*64 + kkE];
      #pragma unroll
      for (int nn=0;nn<4;nn++)
        acc[mm][nn] += a.x*br[0][nn] + a.y*br[1][nn] + a.z*br[2][nn] + a.w*br[3][nn];
    }
  }
  #pragma unroll
  for (int mm=0;mm<4;mm++){
    float4 o;
    o.x = lrelu(acc[mm][0]); o.y = lrelu(acc[mm][1]);
    o.z = lrelu(acc[mm][2]); o.w = lrelu(acc[mm][3]);
    *(float4*)&A1[(m0+mm)*64 + (n0 ^ swz)] = o;
  }
  __syncthreads();
  #pragma unroll
  for (int i=0;i<4;i++) ((float4*)Wb)[i*256 + t] = ((const float4*)nu2_w)[i*256 + t];
  __syncthreads();

  // GEMM2: s_new = x*se_w + se_b + leaky(h1 @ nu2_w + nu2_b)
  {
    float4 b2 = *(const float4*)&nu2_b[n0];
    #pragma unroll
    for (int mm=0;mm<4;mm++){ acc[mm][0]=b2.x; acc[mm][1]=b2.y; acc[mm][2]=b2.z; acc[mm][3]=b2.w; }
  }
  for (int kk0=0;kk0<64;kk0+=4){
    int kkE = kk0 ^ swz;
    float br[4][4];
    #pragma unroll
    for (int i=0;i<4;i++){
      float4 u = *(const float4*)&Wb[(kk0+i)*64 + n0];
      br[i][0]=u.x; br[i][1]=u.y; br[i][2]=u.z; br[i][3]=u.w;
    }
    #pragma unroll
    for (int mm=0;mm<4;mm++){
      float4 a = *(const float4*)&A1[(m0+mm)*64 + kkE];
      #pragma unroll
      for (int nn=0;nn<4;nn++)
        acc[mm][nn] += a.x*br[0][nn] + a.y*br[1][nn] + a.z*br[2][nn] + a.w*br[3][nn];
    }
  }
  {
    float4 sw4 = *(const float4*)&se_w[n0];
    float4 sb4 = *(const float4*)&se_b[n0];
    #pragma unroll
    for (int mm=0;mm<4;mm++){
      float4 o;
      o.x = xr[mm]*sw4.x + sb4.x + lrelu(acc[mm][0]);
      o.y = xr[mm]*sw4.y + sb4.y + lrelu(acc[mm][1]);
      o.z = xr[mm]*sw4.z + sb4.z + lrelu(acc[mm][2]);
      o.w = xr[mm]*sw4.w + sb4.w + lrelu(acc[mm][3]);
      *(float4*)&A0[(m0+mm)*64 + (n0 ^ swz)] = o;
    }
  }
  __syncthreads();
  #pragma unroll
  for (int i=0;i<8;i++) ((float4*)Wb)[i*256 + t] = ((const float4*)p1_w)[i*256 + t];
  __syncthreads();

  // GEMM3: p = leaky(s_new @ p1_w + p1_b), column-sum over rows
  int n0b = (t>>4)*8;
  float acc3[4][8];
  {
    float4 u = *(const float4*)&p1_b[n0b];
    float4 v = *(const float4*)&p1_b[n0b+4];
    #pragma unroll
    for (int mm=0;mm<4;mm++){
      acc3[mm][0]=u.x; acc3[mm][1]=u.y; acc3[mm][2]=u.z; acc3[mm][3]=u.w;
      acc3[mm][4]=v.x; acc3[mm][5]=v.y; acc3[mm][6]=v.z; acc3[mm][7]=v.w;
    }
  }
  for (int kk0=0;kk0<64;kk0+=4){
    int kkE = kk0 ^ swz;
    float br[4][8];
    #pragma unroll
    for (int i=0;i<4;i++){
      float4 u = *(const float4*)&Wb[(kk0+i)*128 + n0b];
      float4 v = *(const float4*)&Wb[(kk0+i)*128 + n0b+4];
      br[i][0]=u.x; br[i][1]=u.y; br[i][2]=u.z; br[i][3]=u.w;
      br[i][4]=v.x; br[i][5]=v.y; br[i][6]=v.z; br[i][7]=v.w;
    }
    #pragma unroll
    for (int mm=0;mm<4;mm++){
      float4 a = *(const float4*)&A0[(m0+mm)*64 + kkE];
      #pragma unroll
      for (int nn=0;nn<8;nn++)
        acc3[mm][nn] += a.x*br[0][nn] + a.y*br[1][nn] + a.z*br[2][nn] + a.w*br[3][nn];
    }
  }
  #pragma unroll
  for (int nn=0;nn<8;nn++){
    float s = 0.f;
    #pragma unroll
    for (int mm=0;mm<4;mm++) s += lrelu(acc3[mm][nn]);
    atomicAdd(&colsum[n0b+nn], s);
  }
  __syncthreads();
  if (t < 128) atomicAdd(&g_psum[b*NMLP + t], colsum[t]);
}

// ---------------- head: mean over nodes + final linear -----------------------
__global__ void k_head(const float* __restrict__ p2_w, const float* __restrict__ p2_b,
                       float* __restrict__ out) {
  int t = threadIdx.x; // 64 threads: 8 batches x 8 lanes
  int b = t >> 3, l = t & 7;
  float s = 0.f;
  for (int c=l;c<NMLP;c+=8) s += g_psum[b*NMLP + c] * p2_w[c];
  s += __shfl_xor(s, 1, 64);
  s += __shfl_xor(s, 2, 64);
  s += __shfl_xor(s, 4, 64);
  if (l == 0) out[b] = s * (1.f/(float)NNODE) + p2_b[0];
}

extern "C" void kernel_launch(void* const* d_in, const int* in_sizes, int n_in,
                              void* d_out, int out_size, void* d_ws, size_t ws_size,
                              hipStream_t stream) {
  (void)in_sizes; (void)n_in; (void)out_size; (void)d_ws; (void)ws_size;
  const float* sites = (const float*)d_in[0];
  const float* bonds = (const float*)d_in[1];
  const int*   idx1  = (const int*)d_in[2];
  const int*   idx2  = (const int*)d_in[3];
  const int*   uc    = (const int*)d_in[4];
  const float* se_w  = (const float*)d_in[5];
  const float* se_b  = (const float*)d_in[6];
  const float* ee_w  = (const float*)d_in[7];
  const float* ee_b  = (const float*)d_in[8];
  const float* m1a_w = (const float*)d_in[9];
  const float* m1a_b = (const float*)d_in[10];
  const float* m1b_w = (const float*)d_in[11];
  const float* m1b_b = (const float*)d_in[12];
  const float* m2a_w = (const float*)d_in[13];
  const float* m2a_b = (const float*)d_in[14];
  const float* m2b_w = (const float*)d_in[15];
  const float* m2b_b = (const float*)d_in[16];
  const float* att1_w = (const float*)d_in[17];
  const float* att1_b = (const float*)d_in[18];
  const float* att2_w = (const float*)d_in[19];
  const float* att2_b = (const float*)d_in[20];
  const float* nu1_w = (const float*)d_in[21];
  const float* nu1_b = (const float*)d_in[22];
  const float* nu2_w = (const float*)d_in[23];
  const float* nu2_b = (const float*)d_in[24];
  const float* p1_w  = (const float*)d_in[25];
  const float* p1_b  = (const float*)d_in[26];
  const float* p2_w  = (const float*)d_in[27];
  const float* p2_b  = (const float*)d_in[28];

  k_init<<<8, 256, 0, stream>>>();
  k_bucket<<<NE/256, 256, 0, stream>>>(uc, idx2);
  k_scan<<<1, 64, 0, stream>>>();
  k_place<<<NE/256, 256, 0, stream>>>(idx2);
  k_fold<<<1, 640, 0, stream>>>(se_w, se_b, ee_w, ee_b,
                                m1a_w, m1a_b, m2a_w, m2a_b, nu1_w, nu1_b);
  dim3 ge(NE/8, NG);
  k_edge<<<ge, 128, 0, stream>>>(sites, bonds, idx1, idx2,
                                 m1b_w, m1b_b, m2b_w, m2b_b,
                                 att1_w, att1_b, att2_w, att2_b);
  k_gather<<<(NNODE*NB)/4, 256, 0, stream>>>();
  k_node<<<NB*32, 256, 0, stream>>>(sites, se_w, se_b,
                                    nu1_w, nu2_w, nu2_b, p1_w, p1_b);
  k_head<<<1, 64, 0, stream>>>(p2_w, p2_b, (float*)d_out);
}

// Round 6
// 161.117 us; speedup vs baseline: 1.3060x; 1.3060x over previous
//
#include <hip/hip_runtime.h>

#define NB 8
#define NNODE 2048
#define NE 32768
#define NG 4
#define NH 64
#define NMLP 128

typedef _Float16 f16x8 __attribute__((ext_vector_type(8)));
typedef float f32x4 __attribute__((ext_vector_type(4)));

// ---------------- persistent device scratch ----------------------------------
__device__ __align__(16) float g_fold[2*NG*12*64];   // folded layer-1 weights
__device__ __align__(16) float g_bc[2*NG*64];        // folded layer-1 bias
__device__ __align__(16) float g_q1[64];             // se_w @ nu1_w[0:64]
__device__ __align__(16) float g_b1f[64];            // se_b @ nu1_w[0:64] + nu1_b
__device__ __align__(16) float g_em[(size_t)NE*NB*64]; // gated edge messages (paths combined)
__device__ __align__(16) float g_msg[NB*NNODE*64];   // per-node reduced messages
__device__ __align__(16) float g_psum[NB*NMLP];
__device__ int g_elist[NG*NE];
__device__ int g_ecnt[NG];
__device__ int g_ncnt[NNODE];
__device__ int g_noff[NNODE];
__device__ int g_cur[NNODE];
__device__ int g_csr[NE];

__device__ __forceinline__ float lrelu(float x){ return fmaxf(x, 0.01f*x); }

// ---------------- init: zero the small accumulators only ---------------------
__global__ void k_init() {
  int i = blockIdx.x*blockDim.x + threadIdx.x;   // 2048 threads
  if (i < NNODE) g_ncnt[i] = 0;
  if (i < NB*NMLP) g_psum[i] = 0.f;
  if (i < NG) g_ecnt[i] = 0;
}

// ---------------- bucket edges by group (wave-aggregated atomics) ------------
__global__ void k_bucket(const int* __restrict__ uc, const int* __restrict__ idx2) {
  int e = blockIdx.x*blockDim.x + threadIdx.x;
  int lane = threadIdx.x & 63;
  int g = (e < NE) ? uc[e] : -1;
  #pragma unroll
  for (int gg = 0; gg < NG; gg++){
    bool mine = (g == gg);
    unsigned long long mask = __ballot(mine);
    if (mine){
      int leader = __ffsll((unsigned long long)mask) - 1;
      int r = __popcll(mask & ((1ULL << lane) - 1ULL));
      int base = 0;
      if (lane == leader) base = atomicAdd(&g_ecnt[gg], (int)__popcll(mask));
      base = __shfl(base, leader, 64);
      g_elist[gg*NE + base + r] = e;
    }
  }
  if (e < NE) atomicAdd(&g_ncnt[idx2[e]], 1);
}

// ---------------- exclusive scan of node counts (1 wave) ---------------------
__global__ void k_scan() {
  int lane = threadIdx.x;              // 64 lanes, 32 nodes each
  int base = lane * 32;
  int loc[32];
  int s = 0;
  #pragma unroll
  for (int i=0;i<32;i++){ loc[i] = s; s += g_ncnt[base+i]; }
  int tot = s;
  #pragma unroll
  for (int d=1; d<64; d<<=1){
    int v = __shfl_up(tot, d, 64);
    if (lane >= d) tot += v;
  }
  int excl = tot - s;
  #pragma unroll
  for (int i=0;i<32;i++){ int o = excl + loc[i]; g_noff[base+i] = o; g_cur[base+i] = o; }
}

// ---------------- place edges into CSR by receiver ----------------------------
__global__ void k_place(const int* __restrict__ idx2) {
  int e = blockIdx.x*blockDim.x + threadIdx.x;
  if (e < NE) {
    int n = idx2[e];
    int pos = atomicAdd(&g_cur[n], 1);
    g_csr[pos] = e;
  }
}

// ---------------- fold rank-1 / rank-10 inputs through layer-1 weights -------
__global__ void k_fold(const float* __restrict__ se_w, const float* __restrict__ se_b,
                       const float* __restrict__ ee_w, const float* __restrict__ ee_b,
                       const float* __restrict__ m1a_w, const float* __restrict__ m1a_b,
                       const float* __restrict__ m2a_w, const float* __restrict__ m2a_b,
                       const float* __restrict__ nu1_w, const float* __restrict__ nu1_b) {
  int t = threadIdx.x;
  if (t < 512) {
    int p = t>>8, g = (t>>6)&3, j = t&63;
    const float* ma = (p ? m2a_w : m1a_w) + g*160*64;
    const float* mb = (p ? m2a_b : m1a_b) + g*64;
    float* W = g_fold + (p*NG+g)*12*64;
    float a0=0.f, a1=0.f, bc=0.f;
    for (int k=0;k<64;k++){
      float sw = se_w[k], sb = se_b[k];
      float w0 = ma[k*64+j], w1 = ma[(64+k)*64+j];
      a0 += sw*w0; a1 += sw*w1; bc += sb*(w0+w1);
    }
    W[0*64+j]=a0; W[1*64+j]=a1;
    for (int c=0;c<10;c++){
      float pc=0.f;
      for (int u=0;u<32;u++) pc += ee_w[c*32+u]*ma[(128+u)*64+j];
      W[(2+c)*64+j]=pc;
    }
    for (int u=0;u<32;u++) bc += ee_b[u]*ma[(128+u)*64+j];
    g_bc[(p*NG+g)*64+j] = bc + mb[j];
  } else if (t < 576) {
    int j = t - 512;
    float q=0.f, bf=0.f;
    for (int k=0;k<64;k++){ float w = nu1_w[k*64+j]; q += se_w[k]*w; bf += se_b[k]*w; }
    g_q1[j]=q; g_b1f[j]=bf + nu1_b[j];
  }
}

// ---------------- edge kernel: 8 edges x 8 batches = 64 rows per block -------
// scalar folded layer1 -> wave-private LDS (XOR swizzle) -> split-fp16 MFMA
// 64x64 GEMM -> leaky -> shfl-reduce attention gate -> combine paths -> store
__global__ __launch_bounds__(128) void k_edge(
    const float* __restrict__ sites, const float* __restrict__ bonds,
    const int* __restrict__ idx1, const int* __restrict__ idx2,
    const float* __restrict__ m1b_w, const float* __restrict__ m1b_b,
    const float* __restrict__ m2b_w, const float* __restrict__ m2b_b,
    const float* __restrict__ att1_w, const float* __restrict__ att1_b,
    const float* __restrict__ att2_w, const float* __restrict__ att2_b) {
  int g = blockIdx.y;
  int cnt = g_ecnt[g];
  int e8 = blockIdx.x * 8;
  if (e8 >= cnt) return;

  __shared__ __align__(16) float hA[64*64];
  __shared__ __align__(16) float fls[64*12];
  __shared__ int sidx[64];

  int t = threadIdx.x;
  int l = t & 63;
  int wv = t >> 6;
  int l15 = l & 15;
  int lg  = l >> 4;          // 0..3
  int swzR = l15 << 2;

  if (t < 64) {
    int r = t, ei = r>>3, b = r&7;
    int eslot = e8 + ei;
    bool valid = eslot < cnt;
    int e = g_elist[g*NE + (valid ? eslot : e8)];
    int i1 = idx1[e], i2 = idx2[e];
    float d = bonds[b*NE + e];
    fls[r*12+0] = sites[b*NNODE + i1];
    fls[r*12+1] = sites[b*NNODE + i2];
    sidx[r] = valid ? (e*NB + b)*64 : -1;
    #pragma unroll
    for (int c=0;c<10;c++){
      float dd = d - c*(10.f/9.f);
      fls[r*12+2+c] = __expf(-dd*dd);
    }
  }
  __syncthreads();

  f32x4 accP[2][2][4];   // [path][mt][nt]

  #pragma unroll
  for (int p=0;p<2;p++){
    const float* W2g = (p ? m2b_w : m1b_w) + g*64*64;
    const float* b2g = (p ? m2b_b : m1b_b) + g*64;
    const float* Wf  = g_fold + (p*NG+g)*12*64;
    float w1r[12];
    #pragma unroll
    for (int r=0;r<12;r++) w1r[r] = Wf[r*64+l];
    float bcr = g_bc[(p*NG+g)*64+l];

    // layer 1: lane = output column k; wave-private rows [wv*32, wv*32+32)
    for (int m = wv*32; m < wv*32 + 32; m++){
      const float4 fa = *(const float4*)&fls[m*12];
      const float4 fb = *(const float4*)&fls[m*12+4];
      const float4 fc = *(const float4*)&fls[m*12+8];
      float hv = bcr
        + fa.x*w1r[0] + fa.y*w1r[1] + fa.z*w1r[2] + fa.w*w1r[3]
        + fb.x*w1r[4] + fb.y*w1r[5] + fb.z*w1r[6] + fb.w*w1r[7]
        + fc.x*w1r[8] + fc.y*w1r[9] + fc.z*w1r[10] + fc.w*w1r[11];
      hA[m*64 + (l ^ ((m&15)<<2))] = lrelu(hv);
    }

    // B fragments (hi/lo) straight from global; col = nt*16+l15, k = kb*32+lg*8+j
    f16x8 bhi[4][2], blo[4][2];
    #pragma unroll
    for (int nt=0;nt<4;nt++){
      int c = nt*16 + l15;
      #pragma unroll
      for (int kb=0;kb<2;kb++){
        int k0 = kb*32 + lg*8;
        f16x8 bh8, bl8;
        #pragma unroll
        for (int j=0;j<8;j++){
          float w = W2g[(k0+j)*64 + c];
          _Float16 hi = (_Float16)w;
          bh8[j] = hi;
          bl8[j] = (_Float16)(w - (float)hi);
        }
        bhi[nt][kb] = bh8; blo[nt][kb] = bl8;
      }
    }

    #pragma unroll
    for (int mt=0;mt<2;mt++){
      int R = wv*32 + mt*16 + l15;
      f16x8 ahi[2], alo[2];
      #pragma unroll
      for (int kb=0;kb<2;kb++){
        int k0 = kb*32 + lg*8;
        const float4 f0 = *(const float4*)&hA[R*64 + ((k0    ) ^ swzR)];
        const float4 f1 = *(const float4*)&hA[R*64 + ((k0 + 4) ^ swzR)];
        f16x8 hi8, lo8;
        float v0;
        v0=f0.x; hi8[0]=(_Float16)v0; lo8[0]=(_Float16)(v0-(float)hi8[0]);
        v0=f0.y; hi8[1]=(_Float16)v0; lo8[1]=(_Float16)(v0-(float)hi8[1]);
        v0=f0.z; hi8[2]=(_Float16)v0; lo8[2]=(_Float16)(v0-(float)hi8[2]);
        v0=f0.w; hi8[3]=(_Float16)v0; lo8[3]=(_Float16)(v0-(float)hi8[3]);
        v0=f1.x; hi8[4]=(_Float16)v0; lo8[4]=(_Float16)(v0-(float)hi8[4]);
        v0=f1.y; hi8[5]=(_Float16)v0; lo8[5]=(_Float16)(v0-(float)hi8[5]);
        v0=f1.z; hi8[6]=(_Float16)v0; lo8[6]=(_Float16)(v0-(float)hi8[6]);
        v0=f1.w; hi8[7]=(_Float16)v0; lo8[7]=(_Float16)(v0-(float)hi8[7]);
        ahi[kb]=hi8; alo[kb]=lo8;
      }
      #pragma unroll
      for (int nt=0;nt<4;nt++){
        float bias = b2g[nt*16 + l15];
        f32x4 acc = {bias, bias, bias, bias};
        acc = __builtin_amdgcn_mfma_f32_16x16x32_f16(ahi[0], bhi[nt][0], acc, 0,0,0);
        acc = __builtin_amdgcn_mfma_f32_16x16x32_f16(ahi[1], bhi[nt][1], acc, 0,0,0);
        acc = __builtin_amdgcn_mfma_f32_16x16x32_f16(ahi[0], blo[nt][0], acc, 0,0,0);
        acc = __builtin_amdgcn_mfma_f32_16x16x32_f16(ahi[1], blo[nt][1], acc, 0,0,0);
        acc = __builtin_amdgcn_mfma_f32_16x16x32_f16(alo[0], bhi[nt][0], acc, 0,0,0);
        acc = __builtin_amdgcn_mfma_f32_16x16x32_f16(alo[1], bhi[nt][1], acc, 0,0,0);
        accP[p][mt][nt] = acc;
      }
    }
  }

  // epilogue: leaky -> attention row-dot (shfl over the 16-lane col group)
  // -> sigmoid gate -> combine paths -> store
  float comb[2][4][4];
  #pragma unroll
  for (int mt=0;mt<2;mt++)
    #pragma unroll
    for (int nt=0;nt<4;nt++)
      #pragma unroll
      for (int r=0;r<4;r++) comb[mt][nt][r] = 0.f;

  #pragma unroll
  for (int p=0;p<2;p++){
    float ab = p ? att2_b[0] : att1_b[0];
    const float* aw = p ? att2_w : att1_w;
    #pragma unroll
    for (int mt=0;mt<2;mt++){
      float o[4][4];
      float pa[4] = {0.f,0.f,0.f,0.f};
      #pragma unroll
      for (int nt=0;nt<4;nt++){
        float w = aw[nt*16 + l15];
        #pragma unroll
        for (int r=0;r<4;r++){
          float ov = lrelu(accP[p][mt][nt][r]);
          o[nt][r] = ov;
          pa[r] += ov * w;
        }
      }
      #pragma unroll
      for (int r=0;r<4;r++){
        float s = pa[r];
        s += __shfl_xor(s, 1, 64);
        s += __shfl_xor(s, 2, 64);
        s += __shfl_xor(s, 4, 64);
        s += __shfl_xor(s, 8, 64);
        float sg = 1.f/(1.f + __expf(-(s + ab)));
        #pragma unroll
        for (int nt=0;nt<4;nt++) comb[mt][nt][r] += sg * o[nt][r];
      }
    }
  }

  #pragma unroll
  for (int mt=0;mt<2;mt++){
    #pragma unroll
    for (int r=0;r<4;r++){
      int R = wv*32 + mt*16 + lg*4 + r;
      int sb = sidx[R];
      if (sb >= 0){
        #pragma unroll
        for (int nt=0;nt<4;nt++) g_em[sb + nt*16 + l15] = comb[mt][nt][r];
      }
    }
  }
}

// ---------------- gather: CSR segment-reduce, no atomics ---------------------
__global__ __launch_bounds__(256) void k_gather() {
  int w = blockIdx.x*4 + (threadIdx.x >> 6);
  int lane = threadIdx.x & 63;
  int n = w >> 3, b = w & 7;
  int off = g_noff[n], deg = g_ncnt[n];
  float s0 = 0.f, s1 = 0.f;
  int i = 0;
  for (; i+2 <= deg; i += 2){
    int e0 = g_csr[off+i], e1 = g_csr[off+i+1];
    s0 += g_em[(size_t)(e0*NB + b)*64 + lane];
    s1 += g_em[(size_t)(e1*NB + b)*64 + lane];
  }
  if (i < deg){
    int e0 = g_csr[off+i];
    s0 += g_em[(size_t)(e0*NB + b)*64 + lane];
  }
  g_msg[(b*NNODE + n)*64 + lane] = s0 + s1;
}

// ---------------- node kernel: 64 nodes/block, 3 chained GEMMs ---------------
__global__ __launch_bounds__(256) void k_node(
    const float* __restrict__ sites,
    const float* __restrict__ se_w, const float* __restrict__ se_b,
    const float* __restrict__ nu1_w, const float* __restrict__ nu2_w,
    const float* __restrict__ nu2_b,
    const float* __restrict__ p1_w, const float* __restrict__ p1_b) {
  __shared__ __align__(16) float A0[64*64];
  __shared__ __align__(16) float A1[64*64];
  __shared__ __align__(16) float Wb[64*128];
  __shared__ float xs[64];
  __shared__ float colsum[128];
  int t = threadIdx.x;
  int b = blockIdx.x >> 5;
  int nbase = (blockIdx.x & 31) * 64;

  #pragma unroll
  for (int i=0;i<4;i++){
    int idx4 = i*256 + t;
    int row = idx4 >> 4;
    int kb = (idx4 & 15) * 4;
    float4 v = *(const float4*)&g_msg[(b*NNODE + nbase + row)*64 + kb];
    *(float4*)&A0[row*64 + (kb ^ (((row>>3)&7)<<2))] = v;
  }
  if (t < 64) xs[t] = sites[b*NNODE + nbase + t];
  if (t < 128) colsum[t] = 0.f;
  #pragma unroll
  for (int i=0;i<4;i++) ((float4*)Wb)[i*256 + t] = ((const float4*)(nu1_w + 64*64))[i*256 + t];
  __syncthreads();

  int m0 = (t&15)*4;
  int swz = ((m0>>3)&7)<<2;
  int n0 = (t>>4)*4;
  float xr[4];
  #pragma unroll
  for (int mm=0;mm<4;mm++) xr[mm] = xs[m0+mm];

  // GEMM1: h1 = leaky(x*q1 + msg @ nu1_w[64:] + b1f)
  float acc[4][4];
  {
    float4 q  = *(const float4*)&g_q1[n0];
    float4 bf = *(const float4*)&g_b1f[n0];
    #pragma unroll
    for (int mm=0;mm<4;mm++){
      acc[mm][0] = xr[mm]*q.x + bf.x;
      acc[mm][1] = xr[mm]*q.y + bf.y;
      acc[mm][2] = xr[mm]*q.z + bf.z;
      acc[mm][3] = xr[mm]*q.w + bf.w;
    }
  }
  for (int kk0=0;kk0<64;kk0+=4){
    int kkE = kk0 ^ swz;
    float br[4][4];
    #pragma unroll
    for (int i=0;i<4;i++){
      float4 u = *(const float4*)&Wb[(kk0+i)*64 + n0];
      br[i][0]=u.x; br[i][1]=u.y; br[i][2]=u.z; br[i][3]=u.w;
    }
    #pragma unroll
    for (int mm=0;mm<4;mm++){
      float4 a = *(const float4*)&A0[(m0+mm)*64 + kkE];
      #pragma unroll
      for (int nn=0;nn<4;nn++)
        acc[mm][nn] += a.x*br[0][nn] + a.y*br[1][nn] + a.z*br[2][nn] + a.w*br[3][nn];
    }
  }
  #pragma unroll
  for (int mm=0;mm<4;mm++){
    float4 o;
    o.x = lrelu(acc[mm][0]); o.y = lrelu(acc[mm][1]);
    o.z = lrelu(acc[mm][2]); o.w = lrelu(acc[mm][3]);
    *(float4*)&A1[(m0+mm)*64 + (n0 ^ swz)] = o;
  }
  __syncthreads();
  #pragma unroll
  for (int i=0;i<4;i++) ((float4*)Wb)[i*256 + t] = ((const float4*)nu2_w)[i*256 + t];
  __syncthreads();

  // GEMM2: s_new = x*se_w + se_b + leaky(h1 @ nu2_w + nu2_b)
  {
    float4 b2 = *(const float4*)&nu2_b[n0];
    #pragma unroll
    for (int mm=0;mm<4;mm++){ acc[mm][0]=b2.x; acc[mm][1]=b2.y; acc[mm][2]=b2.z; acc[mm][3]=b2.w; }
  }
  for (int kk0=0;kk0<64;kk0+=4){
    int kkE = kk0 ^ swz;
    float br[4][4];
    #pragma unroll
    for (int i=0;i<4;i++){
      float4 u = *(const float4*)&Wb[(kk0+i)*64 + n0];
      br[i][0]=u.x; br[i][1]=u.y; br[i][2]=u.z; br[i][3]=u.w;
    }
    #pragma unroll
    for (int mm=0;mm<4;mm++){
      float4 a = *(const float4*)&A1[(m0+mm)*64 + kkE];
      #pragma unroll
      for (int nn=0;nn<4;nn++)
        acc[mm][nn] += a.x*br[0][nn] + a.y*br[1][nn] + a.z*br[2][nn] + a.w*br[3][nn];
    }
  }
  {
    float4 sw4 = *(const float4*)&se_w[n0];
    float4 sb4 = *(const float4*)&se_b[n0];
    #pragma unroll
    for (int mm=0;mm<4;mm++){
      float4 o;
      o.x = xr[mm]*sw4.x + sb4.x + lrelu(acc[mm][0]);
      o.y = xr[mm]*sw4.y + sb4.y + lrelu(acc[mm][1]);
      o.z = xr[mm]*sw4.z + sb4.z + lrelu(acc[mm][2]);
      o.w = xr[mm]*sw4.w + sb4.w + lrelu(acc[mm][3]);
      *(float4*)&A0[(m0+mm)*64 + (n0 ^ swz)] = o;
    }
  }
  __syncthreads();
  #pragma unroll
  for (int i=0;i<8;i++) ((float4*)Wb)[i*256 + t] = ((const float4*)p1_w)[i*256 + t];
  __syncthreads();

  // GEMM3: p = leaky(s_new @ p1_w + p1_b), column-sum over rows
  int n0b = (t>>4)*8;
  float acc3[4][8];
  {
    float4 u = *(const float4*)&p1_b[n0b];
    float4 v = *(const float4*)&p1_b[n0b+4];
    #pragma unroll
    for (int mm=0;mm<4;mm++){
      acc3[mm][0]=u.x; acc3[mm][1]=u.y; acc3[mm][2]=u.z; acc3[mm][3]=u.w;
      acc3[mm][4]=v.x; acc3[mm][5]=v.y; acc3[mm][6]=v.z; acc3[mm][7]=v.w;
    }
  }
  for (int kk0=0;kk0<64;kk0+=4){
    int kkE = kk0 ^ swz;
    float br[4][8];
    #pragma unroll
    for (int i=0;i<4;i++){
      float4 u = *(const float4*)&Wb[(kk0+i)*128 + n0b];
      float4 v = *(const float4*)&Wb[(kk0+i)*128 + n0b+4];
      br[i][0]=u.x; br[i][1]=u.y; br[i][2]=u.z; br[i][3]=u.w;
      br[i][4]=v.x; br[i][5]=v.y; br[i][6]=v.z; br[i][7]=v.w;
    }
    #pragma unroll
    for (int mm=0;mm<4;mm++){
      float4 a = *(const float4*)&A0[(m0+mm)*64 + kkE];
      #pragma unroll
      for (int nn=0;nn<8;nn++)
        acc3[mm][nn] += a.x*br[0][nn] + a.y*br[1][nn] + a.z*br[2][nn] + a.w*br[3][nn];
    }
  }
  #pragma unroll
  for (int nn=0;nn<8;nn++){
    float s = 0.f;
    #pragma unroll
    for (int mm=0;mm<4;mm++) s += lrelu(acc3[mm][nn]);
    atomicAdd(&colsum[n0b+nn], s);
  }
  __syncthreads();
  if (t < 128) atomicAdd(&g_psum[b*NMLP + t], colsum[t]);
}

// ---------------- head: mean over nodes + final linear -----------------------
__global__ void k_head(const float* __restrict__ p2_w, const float* __restrict__ p2_b,
                       float* __restrict__ out) {
  int t = threadIdx.x; // 64 threads: 8 batches x 8 lanes
  int b = t >> 3, l = t & 7;
  float s = 0.f;
  for (int c=l;c<NMLP;c+=8) s += g_psum[b*NMLP + c] * p2_w[c];
  s += __shfl_xor(s, 1, 64);
  s += __shfl_xor(s, 2, 64);
  s += __shfl_xor(s, 4, 64);
  if (l == 0) out[b] = s * (1.f/(float)NNODE) + p2_b[0];
}

extern "C" void kernel_launch(void* const* d_in, const int* in_sizes, int n_in,
                              void* d_out, int out_size, void* d_ws, size_t ws_size,
                              hipStream_t stream) {
  (void)in_sizes; (void)n_in; (void)out_size; (void)d_ws; (void)ws_size;
  const float* sites = (const float*)d_in[0];
  const float* bonds = (const float*)d_in[1];
  const int*   idx1  = (const int*)d_in[2];
  const int*   idx2  = (const int*)d_in[3];
  const int*   uc    = (const int*)d_in[4];
  const float* se_w  = (const float*)d_in[5];
  const float* se_b  = (const float*)d_in[6];
  const float* ee_w  = (const float*)d_in[7];
  const float* ee_b  = (const float*)d_in[8];
  const float* m1a_w = (const float*)d_in[9];
  const float* m1a_b = (const float*)d_in[10];
  const float* m1b_w = (const float*)d_in[11];
  const float* m1b_b = (const float*)d_in[12];
  const float* m2a_w = (const float*)d_in[13];
  const float* m2a_b = (const float*)d_in[14];
  const float* m2b_w = (const float*)d_in[15];
  const float* m2b_b = (const float*)d_in[16];
  const float* att1_w = (const float*)d_in[17];
  const float* att1_b = (const float*)d_in[18];
  const float* att2_w = (const float*)d_in[19];
  const float* att2_b = (const float*)d_in[20];
  const float* nu1_w = (const float*)d_in[21];
  const float* nu1_b = (const float*)d_in[22];
  const float* nu2_w = (const float*)d_in[23];
  const float* nu2_b = (const float*)d_in[24];
  const float* p1_w  = (const float*)d_in[25];
  const float* p1_b  = (const float*)d_in[26];
  const float* p2_w  = (const float*)d_in[27];
  const float* p2_b  = (const float*)d_in[28];

  k_init<<<8, 256, 0, stream>>>();
  k_bucket<<<NE/256, 256, 0, stream>>>(uc, idx2);
  k_scan<<<1, 64, 0, stream>>>();
  k_place<<<NE/256, 256, 0, stream>>>(idx2);
  k_fold<<<1, 640, 0, stream>>>(se_w, se_b, ee_w, ee_b,
                                m1a_w, m1a_b, m2a_w, m2a_b, nu1_w, nu1_b);
  dim3 ge(NE/8, NG);
  k_edge<<<ge, 128, 0, stream>>>(sites, bonds, idx1, idx2,
                                 m1b_w, m1b_b, m2b_w, m2b_b,
                                 att1_w, att1_b, att2_w, att2_b);
  k_gather<<<(NNODE*NB)/4, 256, 0, stream>>>();
  k_node<<<NB*32, 256, 0, stream>>>(sites, se_w, se_b,
                                    nu1_w, nu2_w, nu2_b, p1_w, p1_b);
  k_head<<<1, 64, 0, stream>>>(p2_w, p2_b, (float*)d_out);
}

// Round 7
// 154.754 us; speedup vs baseline: 1.3597x; 1.0411x over previous
//
#include <hip/hip_runtime.h>

#define NB 8
#define NNODE 2048
#define NE 32768
#define NG 4
#define NH 64
#define NMLP 128

typedef _Float16 f16x8 __attribute__((ext_vector_type(8)));
typedef float f32x4 __attribute__((ext_vector_type(4)));

// ---------------- persistent device scratch ----------------------------------
__device__ __align__(16) float g_fold[2*NG*12*64];   // folded layer-1 weights
__device__ __align__(16) float g_bc[2*NG*64];        // folded layer-1 bias
__device__ __align__(16) float g_q1[64];             // se_w @ nu1_w[0:64]
__device__ __align__(16) float g_b1f[64];            // se_b @ nu1_w[0:64] + nu1_b
__device__ __align__(16) float g_em[(size_t)NE*NB*64]; // gated edge messages
__device__ __align__(16) float g_msg[NB*NNODE*64];   // per-node reduced messages
__device__ __align__(16) float g_psum[NB*NMLP];
// split-fp16 fragment tables (filled once by k_fold2)
__device__ f16x8 g_w1hi[2*NG*4*64];     // layer-1 folded W frags [p][g][nt][lane]
__device__ f16x8 g_w1lo[2*NG*4*64];
__device__ f16x8 g_w2hi[2*NG*4*2*64];   // layer-2 W frags [p][g][nt][kb][lane]
__device__ f16x8 g_w2lo[2*NG*4*2*64];
__device__ int g_elist[NG*NE];
__device__ int g_ecnt[NG];
__device__ int g_ncnt[NNODE];
__device__ int g_noff[NNODE];
__device__ int g_cur[NNODE];
__device__ int g_csr[NE];

__device__ __forceinline__ float lrelu(float x){ return fmaxf(x, 0.01f*x); }

// ---------------- init: zero the small accumulators only ---------------------
__global__ void k_init() {
  int i = blockIdx.x*blockDim.x + threadIdx.x;   // 2048 threads
  if (i < NNODE) g_ncnt[i] = 0;
  if (i < NB*NMLP) g_psum[i] = 0.f;
  if (i < NG) g_ecnt[i] = 0;
}

// ---------------- bucket edges by group (wave-aggregated atomics) ------------
__global__ void k_bucket(const int* __restrict__ uc, const int* __restrict__ idx2) {
  int e = blockIdx.x*blockDim.x + threadIdx.x;
  int lane = threadIdx.x & 63;
  int g = (e < NE) ? uc[e] : -1;
  #pragma unroll
  for (int gg = 0; gg < NG; gg++){
    bool mine = (g == gg);
    unsigned long long mask = __ballot(mine);
    if (mine){
      int leader = __ffsll((unsigned long long)mask) - 1;
      int r = __popcll(mask & ((1ULL << lane) - 1ULL));
      int base = 0;
      if (lane == leader) base = atomicAdd(&g_ecnt[gg], (int)__popcll(mask));
      base = __shfl(base, leader, 64);
      g_elist[gg*NE + base + r] = e;
    }
  }
  if (e < NE) atomicAdd(&g_ncnt[idx2[e]], 1);
}

// ---------------- exclusive scan of node counts (1 wave) ---------------------
__global__ void k_scan() {
  int lane = threadIdx.x;              // 64 lanes, 32 nodes each
  int base = lane * 32;
  int loc[32];
  int s = 0;
  #pragma unroll
  for (int i=0;i<32;i++){ loc[i] = s; s += g_ncnt[base+i]; }
  int tot = s;
  #pragma unroll
  for (int d=1; d<64; d<<=1){
    int v = __shfl_up(tot, d, 64);
    if (lane >= d) tot += v;
  }
  int excl = tot - s;
  #pragma unroll
  for (int i=0;i<32;i++){ int o = excl + loc[i]; g_noff[base+i] = o; g_cur[base+i] = o; }
}

// ---------------- place edges into CSR by receiver ----------------------------
__global__ void k_place(const int* __restrict__ idx2) {
  int e = blockIdx.x*blockDim.x + threadIdx.x;
  if (e < NE) {
    int n = idx2[e];
    int pos = atomicAdd(&g_cur[n], 1);
    g_csr[pos] = e;
  }
}

// ---------------- fold rank-1 / rank-10 inputs through layer-1 weights -------
__global__ void k_fold(const float* __restrict__ se_w, const float* __restrict__ se_b,
                       const float* __restrict__ ee_w, const float* __restrict__ ee_b,
                       const float* __restrict__ m1a_w, const float* __restrict__ m1a_b,
                       const float* __restrict__ m2a_w, const float* __restrict__ m2a_b,
                       const float* __restrict__ nu1_w, const float* __restrict__ nu1_b) {
  int t = threadIdx.x;
  if (t < 512) {
    int p = t>>8, g = (t>>6)&3, j = t&63;
    const float* ma = (p ? m2a_w : m1a_w) + g*160*64;
    const float* mb = (p ? m2a_b : m1a_b) + g*64;
    float* W = g_fold + (p*NG+g)*12*64;
    float a0=0.f, a1=0.f, bc=0.f;
    for (int k=0;k<64;k++){
      float sw = se_w[k], sb = se_b[k];
      float w0 = ma[k*64+j], w1 = ma[(64+k)*64+j];
      a0 += sw*w0; a1 += sw*w1; bc += sb*(w0+w1);
    }
    W[0*64+j]=a0; W[1*64+j]=a1;
    for (int c=0;c<10;c++){
      float pc=0.f;
      for (int u=0;u<32;u++) pc += ee_w[c*32+u]*ma[(128+u)*64+j];
      W[(2+c)*64+j]=pc;
    }
    for (int u=0;u<32;u++) bc += ee_b[u]*ma[(128+u)*64+j];
    g_bc[(p*NG+g)*64+j] = bc + mb[j];
  } else if (t < 576) {
    int j = t - 512;
    float q=0.f, bf=0.f;
    for (int k=0;k<64;k++){ float w = nu1_w[k*64+j]; q += se_w[k]*w; bf += se_b[k]*w; }
    g_q1[j]=q; g_b1f[j]=bf + nu1_b[j];
  }
}

// ---------------- fold2: precompute split-fp16 MFMA weight fragments ---------
// W2 frag: [p][g][nt][kb][lane]  col=nt*16+l15, k=kb*32+lg*8+j
// W1 frag: [p][g][nt][lane]      col=nt*16+l15, k=lg*8+j (k>=12 -> 0)
__global__ void k_fold2(const float* __restrict__ m1b_w, const float* __restrict__ m2b_w) {
  int i = blockIdx.x*blockDim.x + threadIdx.x;   // 24*256 = 6144
  if (i < 2*NG*4*2*64) {
    int lane = i & 63, kb = (i>>6)&1, nt = (i>>7)&3, g = (i>>9)&3, p = (i>>11)&1;
    int l15 = lane & 15, lg = lane >> 4;
    const float* W2g = (p ? m2b_w : m1b_w) + g*64*64;
    int c = nt*16 + l15;
    f16x8 h8, l8;
    #pragma unroll
    for (int j=0;j<8;j++){
      float w = W2g[(kb*32 + lg*8 + j)*64 + c];
      _Float16 hh = (_Float16)w;
      h8[j] = hh; l8[j] = (_Float16)(w - (float)hh);
    }
    g_w2hi[i] = h8; g_w2lo[i] = l8;
  } else if (i < 2*NG*4*2*64 + 2*NG*4*64) {
    int k2 = i - 2*NG*4*2*64;
    int lane = k2 & 63, nt = (k2>>6)&3, g = (k2>>8)&3, p = (k2>>10)&1;
    int l15 = lane & 15, lg = lane >> 4;
    const float* Wf = g_fold + (p*NG+g)*12*64;
    int c = nt*16 + l15;
    f16x8 h8, l8;
    #pragma unroll
    for (int j=0;j<8;j++){
      int k = lg*8 + j;
      float w = (k < 12) ? Wf[k*64 + c] : 0.f;
      _Float16 hh = (_Float16)w;
      h8[j] = hh; l8[j] = (_Float16)(w - (float)hh);
    }
    g_w1hi[k2] = h8; g_w1lo[k2] = l8;
  }
}

// ---------------- edge kernel: 8 edges x 8 batches = 64 rows per block -------
// MFMA layer1 (K=12 padded to 32) -> lrelu -> swizzled LDS -> split-fp16 MFMA
// layer2 -> leaky -> shfl-reduce attention gate -> combine paths -> store
__global__ __launch_bounds__(128) void k_edge(
    const float* __restrict__ sites, const float* __restrict__ bonds,
    const int* __restrict__ idx1, const int* __restrict__ idx2,
    const float* __restrict__ m1b_b, const float* __restrict__ m2b_b,
    const float* __restrict__ att1_w, const float* __restrict__ att1_b,
    const float* __restrict__ att2_w, const float* __restrict__ att2_b) {
  int g = blockIdx.y;
  int cnt = g_ecnt[g];
  int e8 = blockIdx.x * 8;
  if (e8 >= cnt) return;

  __shared__ __align__(16) float hA[64*64];
  __shared__ __align__(16) float fls[64*12];
  __shared__ int sidx[64];

  int t = threadIdx.x;
  int l = t & 63;
  int wv = t >> 6;
  int l15 = l & 15;
  int lg  = l >> 4;          // 0..3
  int swzR = l15 << 2;

  if (t < 64) {
    int r = t, ei = r>>3, b = r&7;
    int eslot = e8 + ei;
    bool valid = eslot < cnt;
    int e = g_elist[g*NE + (valid ? eslot : e8)];
    int i1 = idx1[e], i2 = idx2[e];
    float d = bonds[b*NE + e];
    fls[r*12+0] = sites[b*NNODE + i1];
    fls[r*12+1] = sites[b*NNODE + i2];
    sidx[r] = valid ? (e*NB + b)*64 : -1;
    #pragma unroll
    for (int c=0;c<10;c++){
      float dd = d - c*(10.f/9.f);
      fls[r*12+2+c] = __expf(-dd*dd);
    }
  }
  __syncthreads();

  // ---- feature A-fragments (shared by both paths): row=l15, k=lg*8+j -------
  f16x8 fhi[2], flo[2];
  #pragma unroll
  for (int mt=0;mt<2;mt++){
    f16x8 h8, l8;
    #pragma unroll
    for (int j=0;j<8;j++){ h8[j]=(_Float16)0; l8[j]=(_Float16)0; }
    int R = wv*32 + mt*16 + l15;
    if (lg == 0){
      float4 f0 = *(const float4*)&fls[R*12];
      float4 f1 = *(const float4*)&fls[R*12+4];
      float v;
      v=f0.x; h8[0]=(_Float16)v; l8[0]=(_Float16)(v-(float)h8[0]);
      v=f0.y; h8[1]=(_Float16)v; l8[1]=(_Float16)(v-(float)h8[1]);
      v=f0.z; h8[2]=(_Float16)v; l8[2]=(_Float16)(v-(float)h8[2]);
      v=f0.w; h8[3]=(_Float16)v; l8[3]=(_Float16)(v-(float)h8[3]);
      v=f1.x; h8[4]=(_Float16)v; l8[4]=(_Float16)(v-(float)h8[4]);
      v=f1.y; h8[5]=(_Float16)v; l8[5]=(_Float16)(v-(float)h8[5]);
      v=f1.z; h8[6]=(_Float16)v; l8[6]=(_Float16)(v-(float)h8[6]);
      v=f1.w; h8[7]=(_Float16)v; l8[7]=(_Float16)(v-(float)h8[7]);
    } else if (lg == 1){
      float4 f2 = *(const float4*)&fls[R*12+8];
      float v;
      v=f2.x; h8[0]=(_Float16)v; l8[0]=(_Float16)(v-(float)h8[0]);
      v=f2.y; h8[1]=(_Float16)v; l8[1]=(_Float16)(v-(float)h8[1]);
      v=f2.z; h8[2]=(_Float16)v; l8[2]=(_Float16)(v-(float)h8[2]);
      v=f2.w; h8[3]=(_Float16)v; l8[3]=(_Float16)(v-(float)h8[3]);
    }
    fhi[mt]=h8; flo[mt]=l8;
  }

  f32x4 accP[2][2][4];   // [path][mt][nt]

  #pragma unroll
  for (int p=0;p<2;p++){
    const float* b2g = (p ? m2b_b : m1b_b) + g*64;
    int pg = p*NG + g;

    // ---- layer 1 via MFMA: h[32x64] = feat[32x12pad32] @ W1fold ----
    #pragma unroll
    for (int nt=0;nt<4;nt++){
      int b1 = (pg*4 + nt)*64 + l;
      f16x8 w1h = g_w1hi[b1], w1l = g_w1lo[b1];
      float bias = g_bc[pg*64 + nt*16 + l15];
      #pragma unroll
      for (int mt=0;mt<2;mt++){
        f32x4 a = {bias, bias, bias, bias};
        a = __builtin_amdgcn_mfma_f32_16x16x32_f16(fhi[mt], w1h, a, 0,0,0);
        a = __builtin_amdgcn_mfma_f32_16x16x32_f16(fhi[mt], w1l, a, 0,0,0);
        a = __builtin_amdgcn_mfma_f32_16x16x32_f16(flo[mt], w1h, a, 0,0,0);
        #pragma unroll
        for (int r=0;r<4;r++){
          int R = wv*32 + mt*16 + lg*4 + r;
          hA[R*64 + ((nt*16 + l15) ^ ((R&15)<<2))] = lrelu(a[r]);
        }
      }
    }
    // wave-private rows: no barrier needed (compiler inserts lgkmcnt waits)

    // ---- layer 2: read h back as A-frags (split), MFMA against W2 frags ----
    f16x8 ahi[2][2], alo[2][2];   // [mt][kb]
    #pragma unroll
    for (int mt=0;mt<2;mt++){
      int R = wv*32 + mt*16 + l15;
      #pragma unroll
      for (int kb=0;kb<2;kb++){
        int k0 = kb*32 + lg*8;
        const float4 f0 = *(const float4*)&hA[R*64 + ((k0    ) ^ swzR)];
        const float4 f1 = *(const float4*)&hA[R*64 + ((k0 + 4) ^ swzR)];
        f16x8 hi8, lo8;
        float v0;
        v0=f0.x; hi8[0]=(_Float16)v0; lo8[0]=(_Float16)(v0-(float)hi8[0]);
        v0=f0.y; hi8[1]=(_Float16)v0; lo8[1]=(_Float16)(v0-(float)hi8[1]);
        v0=f0.z; hi8[2]=(_Float16)v0; lo8[2]=(_Float16)(v0-(float)hi8[2]);
        v0=f0.w; hi8[3]=(_Float16)v0; lo8[3]=(_Float16)(v0-(float)hi8[3]);
        v0=f1.x; hi8[4]=(_Float16)v0; lo8[4]=(_Float16)(v0-(float)hi8[4]);
        v0=f1.y; hi8[5]=(_Float16)v0; lo8[5]=(_Float16)(v0-(float)hi8[5]);
        v0=f1.z; hi8[6]=(_Float16)v0; lo8[6]=(_Float16)(v0-(float)hi8[6]);
        v0=f1.w; hi8[7]=(_Float16)v0; lo8[7]=(_Float16)(v0-(float)hi8[7]);
        ahi[mt][kb]=hi8; alo[mt][kb]=lo8;
      }
    }
    #pragma unroll
    for (int nt=0;nt<4;nt++){
      int b2 = ((pg*4 + nt)*2)*64 + l;
      f16x8 bh0 = g_w2hi[b2],    bl0 = g_w2lo[b2];
      f16x8 bh1 = g_w2hi[b2+64], bl1 = g_w2lo[b2+64];
      float bias = b2g[nt*16 + l15];
      #pragma unroll
      for (int mt=0;mt<2;mt++){
        f32x4 acc = {bias, bias, bias, bias};
        acc = __builtin_amdgcn_mfma_f32_16x16x32_f16(ahi[mt][0], bh0, acc, 0,0,0);
        acc = __builtin_amdgcn_mfma_f32_16x16x32_f16(ahi[mt][1], bh1, acc, 0,0,0);
        acc = __builtin_amdgcn_mfma_f32_16x16x32_f16(ahi[mt][0], bl0, acc, 0,0,0);
        acc = __builtin_amdgcn_mfma_f32_16x16x32_f16(ahi[mt][1], bl1, acc, 0,0,0);
        acc = __builtin_amdgcn_mfma_f32_16x16x32_f16(alo[mt][0], bh0, acc, 0,0,0);
        acc = __builtin_amdgcn_mfma_f32_16x16x32_f16(alo[mt][1], bh1, acc, 0,0,0);
        accP[p][mt][nt] = acc;
      }
    }
  }

  // epilogue: leaky -> attention row-dot (shfl over the 16-lane col group)
  // -> sigmoid gate -> combine paths -> store
  float comb[2][4][4];
  #pragma unroll
  for (int mt=0;mt<2;mt++)
    #pragma unroll
    for (int nt=0;nt<4;nt++)
      #pragma unroll
      for (int r=0;r<4;r++) comb[mt][nt][r] = 0.f;

  #pragma unroll
  for (int p=0;p<2;p++){
    float ab = p ? att2_b[0] : att1_b[0];
    const float* aw = p ? att2_w : att1_w;
    #pragma unroll
    for (int mt=0;mt<2;mt++){
      float o[4][4];
      float pa[4] = {0.f,0.f,0.f,0.f};
      #pragma unroll
      for (int nt=0;nt<4;nt++){
        float w = aw[nt*16 + l15];
        #pragma unroll
        for (int r=0;r<4;r++){
          float ov = lrelu(accP[p][mt][nt][r]);
          o[nt][r] = ov;
          pa[r] += ov * w;
        }
      }
      #pragma unroll
      for (int r=0;r<4;r++){
        float s = pa[r];
        s += __shfl_xor(s, 1, 64);
        s += __shfl_xor(s, 2, 64);
        s += __shfl_xor(s, 4, 64);
        s += __shfl_xor(s, 8, 64);
        float sg = 1.f/(1.f + __expf(-(s + ab)));
        #pragma unroll
        for (int nt=0;nt<4;nt++) comb[mt][nt][r] += sg * o[nt][r];
      }
    }
  }

  #pragma unroll
  for (int mt=0;mt<2;mt++){
    #pragma unroll
    for (int r=0;r<4;r++){
      int R = wv*32 + mt*16 + lg*4 + r;
      int sb = sidx[R];
      if (sb >= 0){
        #pragma unroll
        for (int nt=0;nt<4;nt++) g_em[sb + nt*16 + l15] = comb[mt][nt][r];
      }
    }
  }
}

// ---------------- gather: CSR segment-reduce, no atomics ---------------------
__global__ __launch_bounds__(256) void k_gather() {
  int w = blockIdx.x*4 + (threadIdx.x >> 6);
  int lane = threadIdx.x & 63;
  int n = w >> 3, b = w & 7;
  int off = g_noff[n], deg = g_ncnt[n];
  float s0 = 0.f, s1 = 0.f;
  int i = 0;
  for (; i+2 <= deg; i += 2){
    int e0 = g_csr[off+i], e1 = g_csr[off+i+1];
    s0 += g_em[(size_t)(e0*NB + b)*64 + lane];
    s1 += g_em[(size_t)(e1*NB + b)*64 + lane];
  }
  if (i < deg){
    int e0 = g_csr[off+i];
    s0 += g_em[(size_t)(e0*NB + b)*64 + lane];
  }
  g_msg[(b*NNODE + n)*64 + lane] = s0 + s1;
}

// ---------------- node kernel: 64 nodes/block, 3 chained GEMMs ---------------
__global__ __launch_bounds__(256) void k_node(
    const float* __restrict__ sites,
    const float* __restrict__ se_w, const float* __restrict__ se_b,
    const float* __restrict__ nu1_w, const float* __restrict__ nu2_w,
    const float* __restrict__ nu2_b,
    const float* __restrict__ p1_w, const float* __restrict__ p1_b) {
  __shared__ __align__(16) float A0[64*64];
  __shared__ __align__(16) float A1[64*64];
  __shared__ __align__(16) float Wb[64*128];
  __shared__ float xs[64];
  __shared__ float colsum[128];
  int t = threadIdx.x;
  int b = blockIdx.x >> 5;
  int nbase = (blockIdx.x & 31) * 64;

  #pragma unroll
  for (int i=0;i<4;i++){
    int idx4 = i*256 + t;
    int row = idx4 >> 4;
    int kb = (idx4 & 15) * 4;
    float4 v = *(const float4*)&g_msg[(b*NNODE + nbase + row)*64 + kb];
    *(float4*)&A0[row*64 + (kb ^ (((row>>3)&7)<<2))] = v;
  }
  if (t < 64) xs[t] = sites[b*NNODE + nbase + t];
  if (t < 128) colsum[t] = 0.f;
  #pragma unroll
  for (int i=0;i<4;i++) ((float4*)Wb)[i*256 + t] = ((const float4*)(nu1_w + 64*64))[i*256 + t];
  __syncthreads();

  int m0 = (t&15)*4;
  int swz = ((m0>>3)&7)<<2;
  int n0 = (t>>4)*4;
  float xr[4];
  #pragma unroll
  for (int mm=0;mm<4;mm++) xr[mm] = xs[m0+mm];

  // GEMM1: h1 = leaky(x*q1 + msg @ nu1_w[64:] + b1f)
  float acc[4][4];
  {
    float4 q  = *(const float4*)&g_q1[n0];
    float4 bf = *(const float4*)&g_b1f[n0];
    #pragma unroll
    for (int mm=0;mm<4;mm++){
      acc[mm][0] = xr[mm]*q.x + bf.x;
      acc[mm][1] = xr[mm]*q.y + bf.y;
      acc[mm][2] = xr[mm]*q.z + bf.z;
      acc[mm][3] = xr[mm]*q.w + bf.w;
    }
  }
  for (int kk0=0;kk0<64;kk0+=4){
    int kkE = kk0 ^ swz;
    float br[4][4];
    #pragma unroll
    for (int i=0;i<4;i++){
      float4 u = *(const float4*)&Wb[(kk0+i)*64 + n0];
      br[i][0]=u.x; br[i][1]=u.y; br[i][2]=u.z; br[i][3]=u.w;
    }
    #pragma unroll
    for (int mm=0;mm<4;mm++){
      float4 a = *(const float4*)&A0[(m0+mm)*64 + kkE];
      #pragma unroll
      for (int nn=0;nn<4;nn++)
        acc[mm][nn] += a.x*br[0][nn] + a.y*br[1][nn] + a.z*br[2][nn] + a.w*br[3][nn];
    }
  }
  #pragma unroll
  for (int mm=0;mm<4;mm++){
    float4 o;
    o.x = lrelu(acc[mm][0]); o.y = lrelu(acc[mm][1]);
    o.z = lrelu(acc[mm][2]); o.w = lrelu(acc[mm][3]);
    *(float4*)&A1[(m0+mm)*64 + (n0 ^ swz)] = o;
  }
  __syncthreads();
  #pragma unroll
  for (int i=0;i<4;i++) ((float4*)Wb)[i*256 + t] = ((const float4*)nu2_w)[i*256 + t];
  __syncthreads();

  // GEMM2: s_new = x*se_w + se_b + leaky(h1 @ nu2_w + nu2_b)
  {
    float4 b2 = *(const float4*)&nu2_b[n0];
    #pragma unroll
    for (int mm=0;mm<4;mm++){ acc[mm][0]=b2.x; acc[mm][1]=b2.y; acc[mm][2]=b2.z; acc[mm][3]=b2.w; }
  }
  for (int kk0=0;kk0<64;kk0+=4){
    int kkE = kk0 ^ swz;
    float br[4][4];
    #pragma unroll
    for (int i=0;i<4;i++){
      float4 u = *(const float4*)&Wb[(kk0+i)*64 + n0];
      br[i][0]=u.x; br[i][1]=u.y; br[i][2]=u.z; br[i][3]=u.w;
    }
    #pragma unroll
    for (int mm=0;mm<4;mm++){
      float4 a = *(const float4*)&A1[(m0+mm)*64 + kkE];
      #pragma unroll
      for (int nn=0;nn<4;nn++)
        acc[mm][nn] += a.x*br[0][nn] + a.y*br[1][nn] + a.z*br[2][nn] + a.w*br[3][nn];
    }
  }
  {
    float4 sw4 = *(const float4*)&se_w[n0];
    float4 sb4 = *(const float4*)&se_b[n0];
    #pragma unroll
    for (int mm=0;mm<4;mm++){
      float4 o;
      o.x = xr[mm]*sw4.x + sb4.x + lrelu(acc[mm][0]);
      o.y = xr[mm]*sw4.y + sb4.y + lrelu(acc[mm][1]);
      o.z = xr[mm]*sw4.z + sb4.z + lrelu(acc[mm][2]);
      o.w = xr[mm]*sw4.w + sb4.w + lrelu(acc[mm][3]);
      *(float4*)&A0[(m0+mm)*64 + (n0 ^ swz)] = o;
    }
  }
  __syncthreads();
  #pragma unroll
  for (int i=0;i<8;i++) ((float4*)Wb)[i*256 + t] = ((const float4*)p1_w)[i*256 + t];
  __syncthreads();

  // GEMM3: p = leaky(s_new @ p1_w + p1_b), column-sum over rows
  int n0b = (t>>4)*8;
  float acc3[4][8];
  {
    float4 u = *(const float4*)&p1_b[n0b];
    float4 v = *(const float4*)&p1_b[n0b+4];
    #pragma unroll
    for (int mm=0;mm<4;mm++){
      acc3[mm][0]=u.x; acc3[mm][1]=u.y; acc3[mm][2]=u.z; acc3[mm][3]=u.w;
      acc3[mm][4]=v.x; acc3[mm][5]=v.y; acc3[mm][6]=v.z; acc3[mm][7]=v.w;
    }
  }
  for (int kk0=0;kk0<64;kk0+=4){
    int kkE = kk0 ^ swz;
    float br[4][8];
    #pragma unroll
    for (int i=0;i<4;i++){
      float4 u = *(const float4*)&Wb[(kk0+i)*128 + n0b];
      float4 v = *(const float4*)&Wb[(kk0+i)*128 + n0b+4];
      br[i][0]=u.x; br[i][1]=u.y; br[i][2]=u.z; br[i][3]=u.w;
      br[i][4]=v.x; br[i][5]=v.y; br[i][6]=v.z; br[i][7]=v.w;
    }
    #pragma unroll
    for (int mm=0;mm<4;mm++){
      float4 a = *(const float4*)&A0[(m0+mm)*64 + kkE];
      #pragma unroll
      for (int nn=0;nn<8;nn++)
        acc3[mm][nn] += a.x*br[0][nn] + a.y*br[1][nn] + a.z*br[2][nn] + a.w*br[3][nn];
    }
  }
  #pragma unroll
  for (int nn=0;nn<8;nn++){
    float s = 0.f;
    #pragma unroll
    for (int mm=0;mm<4;mm++) s += lrelu(acc3[mm][nn]);
    atomicAdd(&colsum[n0b+nn], s);
  }
  __syncthreads();
  if (t < 128) atomicAdd(&g_psum[b*NMLP + t], colsum[t]);
}

// ---------------- head: mean over nodes + final linear -----------------------
__global__ void k_head(const float* __restrict__ p2_w, const float* __restrict__ p2_b,
                       float* __restrict__ out) {
  int t = threadIdx.x; // 64 threads: 8 batches x 8 lanes
  int b = t >> 3, l = t & 7;
  float s = 0.f;
  for (int c=l;c<NMLP;c+=8) s += g_psum[b*NMLP + c] * p2_w[c];
  s += __shfl_xor(s, 1, 64);
  s += __shfl_xor(s, 2, 64);
  s += __shfl_xor(s, 4, 64);
  if (l == 0) out[b] = s * (1.f/(float)NNODE) + p2_b[0];
}

extern "C" void kernel_launch(void* const* d_in, const int* in_sizes, int n_in,
                              void* d_out, int out_size, void* d_ws, size_t ws_size,
                              hipStream_t stream) {
  (void)in_sizes; (void)n_in; (void)out_size; (void)d_ws; (void)ws_size;
  const float* sites = (const float*)d_in[0];
  const float* bonds = (const float*)d_in[1];
  const int*   idx1  = (const int*)d_in[2];
  const int*   idx2  = (const int*)d_in[3];
  const int*   uc    = (const int*)d_in[4];
  const float* se_w  = (const float*)d_in[5];
  const float* se_b  = (const float*)d_in[6];
  const float* ee_w  = (const float*)d_in[7];
  const float* ee_b  = (const float*)d_in[8];
  const float* m1a_w = (const float*)d_in[9];
  const float* m1a_b = (const float*)d_in[10];
  const float* m1b_w = (const float*)d_in[11];
  const float* m1b_b = (const float*)d_in[12];
  const float* m2a_w = (const float*)d_in[13];
  const float* m2a_b = (const float*)d_in[14];
  const float* m2b_w = (const float*)d_in[15];
  const float* m2b_b = (const float*)d_in[16];
  const float* att1_w = (const float*)d_in[17];
  const float* att1_b = (const float*)d_in[18];
  const float* att2_w = (const float*)d_in[19];
  const float* att2_b = (const float*)d_in[20];
  const float* nu1_w = (const float*)d_in[21];
  const float* nu1_b = (const float*)d_in[22];
  const float* nu2_w = (const float*)d_in[23];
  const float* nu2_b = (const float*)d_in[24];
  const float* p1_w  = (const float*)d_in[25];
  const float* p1_b  = (const float*)d_in[26];
  const float* p2_w  = (const float*)d_in[27];
  const float* p2_b  = (const float*)d_in[28];

  k_init<<<8, 256, 0, stream>>>();
  k_bucket<<<NE/256, 256, 0, stream>>>(uc, idx2);
  k_scan<<<1, 64, 0, stream>>>();
  k_place<<<NE/256, 256, 0, stream>>>(idx2);
  k_fold<<<1, 640, 0, stream>>>(se_w, se_b, ee_w, ee_b,
                                m1a_w, m1a_b, m2a_w, m2a_b, nu1_w, nu1_b);
  k_fold2<<<24, 256, 0, stream>>>(m1b_w, m2b_w);
  dim3 ge(NE/8, NG);
  k_edge<<<ge, 128, 0, stream>>>(sites, bonds, idx1, idx2,
                                 m1b_b, m2b_b,
                                 att1_w, att1_b, att2_w, att2_b);
  k_gather<<<(NNODE*NB)/4, 256, 0, stream>>>();
  k_node<<<NB*32, 256, 0, stream>>>(sites, se_w, se_b,
                                    nu1_w, nu2_w, nu2_b, p1_w, p1_b);
  k_head<<<1, 64, 0, stream>>>(p2_w, p2_b, (float*)d_out);
}

// Round 9
// 143.972 us; speedup vs baseline: 1.4615x; 1.0749x over previous
//
#include <hip/hip_runtime.h>

#define NB 8
#define NNODE 2048
#define NE 32768
#define NG 4
#define NH 64
#define NMLP 128

typedef _Float16 f16x8 __attribute__((ext_vector_type(8)));
typedef float f32x4 __attribute__((ext_vector_type(4)));

// ---------------- persistent device scratch ----------------------------------
__device__ __align__(16) float g_bc[2*NG*64];        // folded layer-1 bias
__device__ __align__(16) float g_q1[64];             // se_w @ nu1_w[0:64]
__device__ __align__(16) float g_b1f[64];            // se_b @ nu1_w[0:64] + nu1_b
__device__ __align__(16) _Float16 g_em16[(size_t)NE*NB*64]; // gated edge messages (fp16)
__device__ __align__(16) float g_msg[NB*NNODE*64];   // per-node reduced messages
__device__ __align__(16) float g_psum[NB*NMLP];
// split-fp16 fragment tables (filled once by k_foldall)
__device__ f16x8 g_w1hi[2*NG*4*64];     // layer-1 folded W frags [p][g][nt][lane]
__device__ f16x8 g_w1lo[2*NG*4*64];
__device__ f16x8 g_w2hi[2*NG*4*2*64];   // layer-2 W frags [p][g][nt][kb][lane]
__device__ f16x8 g_w2lo[2*NG*4*2*64];
__device__ f16x8 g_wn1hi[4*2*64];       // nu1_w[64:] frags [nt][kb][lane]
__device__ f16x8 g_wn1lo[4*2*64];
__device__ f16x8 g_wn2hi[4*2*64];       // nu2_w frags
__device__ f16x8 g_wn2lo[4*2*64];
__device__ f16x8 g_wp1hi[8*2*64];       // p1_w frags [nt8][kb][lane]
__device__ f16x8 g_wp1lo[8*2*64];
__device__ int g_elist[NG*NE];
__device__ int g_ecnt[NG];
__device__ int g_ncnt[NNODE];
__device__ int g_noff[NNODE];
__device__ int g_cur[NNODE];
__device__ int g_csr[NE];

__device__ __forceinline__ float lrelu(float x){ return fmaxf(x, 0.01f*x); }

// ---------------- init: zero the small accumulators only ---------------------
__global__ void k_init() {
  int i = blockIdx.x*blockDim.x + threadIdx.x;   // 2048 threads
  if (i < NNODE) g_ncnt[i] = 0;
  if (i < NB*NMLP) g_psum[i] = 0.f;
  if (i < NG) g_ecnt[i] = 0;
}

// ---------------- bucket edges by group (wave-aggregated atomics) ------------
__global__ void k_bucket(const int* __restrict__ uc, const int* __restrict__ idx2) {
  int e = blockIdx.x*blockDim.x + threadIdx.x;
  int lane = threadIdx.x & 63;
  int g = (e < NE) ? uc[e] : -1;
  #pragma unroll
  for (int gg = 0; gg < NG; gg++){
    bool mine = (g == gg);
    unsigned long long mask = __ballot(mine);
    if (mine){
      int leader = __ffsll((unsigned long long)mask) - 1;
      int r = __popcll(mask & ((1ULL << lane) - 1ULL));
      int base = 0;
      if (lane == leader) base = atomicAdd(&g_ecnt[gg], (int)__popcll(mask));
      base = __shfl(base, leader, 64);
      g_elist[gg*NE + base + r] = e;
    }
  }
  if (e < NE) atomicAdd(&g_ncnt[idx2[e]], 1);
}

// ---------------- exclusive scan of node counts (1 wave) ---------------------
__global__ void k_scan() {
  int lane = threadIdx.x;              // 64 lanes, 32 nodes each
  int base = lane * 32;
  int loc[32];
  int s = 0;
  #pragma unroll
  for (int i=0;i<32;i++){ loc[i] = s; s += g_ncnt[base+i]; }
  int tot = s;
  #pragma unroll
  for (int d=1; d<64; d<<=1){
    int v = __shfl_up(tot, d, 64);
    if (lane >= d) tot += v;
  }
  int excl = tot - s;
  #pragma unroll
  for (int i=0;i<32;i++){ int o = excl + loc[i]; g_noff[base+i] = o; g_cur[base+i] = o; }
}

// ---------------- place edges into CSR by receiver ----------------------------
__global__ void k_place(const int* __restrict__ idx2) {
  int e = blockIdx.x*blockDim.x + threadIdx.x;
  if (e < NE) {
    int n = idx2[e];
    int pos = atomicAdd(&g_cur[n], 1);
    g_csr[pos] = e;
  }
}

// ---------------- foldall: fold rank-1/rank-10 inputs + build ALL frag tables -
// phase1 (t<576): fold layer-1 weights into LDS + g_bc, q1/b1f
// phase2 (all):   split-fp16 fragment tables, 8192 total entries:
//   [0,4096)      edge W2  (2p x 4g x 4nt x 2kb x 64)
//   [4096,6144)   edge W1  (2p x 4g x 4nt x 64)
//   [6144,6656)   node nu1 (4nt x 2kb x 64)
//   [6656,7168)   node nu2 (4nt x 2kb x 64)
//   [7168,8192)   node p1  (8nt x 2kb x 64)
__global__ __launch_bounds__(1024) void k_foldall(
    const float* __restrict__ se_w, const float* __restrict__ se_b,
    const float* __restrict__ ee_w, const float* __restrict__ ee_b,
    const float* __restrict__ m1a_w, const float* __restrict__ m1a_b,
    const float* __restrict__ m2a_w, const float* __restrict__ m2a_b,
    const float* __restrict__ nu1_w, const float* __restrict__ nu1_b,
    const float* __restrict__ m1b_w, const float* __restrict__ m2b_w,
    const float* __restrict__ nu2_w, const float* __restrict__ p1_w) {
  __shared__ float sfold[2*NG*12*64];   // 24 KB
  int t = threadIdx.x;
  if (t < 512) {
    int p = t>>8, g = (t>>6)&3, j = t&63;
    const float* ma = (p ? m2a_w : m1a_w) + g*160*64;
    const float* mb = (p ? m2a_b : m1a_b) + g*64;
    float* W = sfold + (p*NG+g)*12*64;
    float a0=0.f, a1=0.f, bc=0.f;
    for (int k=0;k<64;k++){
      float sw = se_w[k], sb = se_b[k];
      float w0 = ma[k*64+j], w1 = ma[(64+k)*64+j];
      a0 += sw*w0; a1 += sw*w1; bc += sb*(w0+w1);
    }
    W[0*64+j]=a0; W[1*64+j]=a1;
    for (int c=0;c<10;c++){
      float pc=0.f;
      for (int u=0;u<32;u++) pc += ee_w[c*32+u]*ma[(128+u)*64+j];
      W[(2+c)*64+j]=pc;
    }
    for (int u=0;u<32;u++) bc += ee_b[u]*ma[(128+u)*64+j];
    g_bc[(p*NG+g)*64+j] = bc + mb[j];
  } else if (t < 576) {
    int j = t - 512;
    float q=0.f, bf=0.f;
    for (int k=0;k<64;k++){ float w = nu1_w[k*64+j]; q += se_w[k]*w; bf += se_b[k]*w; }
    g_q1[j]=q; g_b1f[j]=bf + nu1_b[j];
  }
  __syncthreads();

  for (int i = t; i < 8192; i += 1024) {
    if (i < 4096) {               // edge W2 frags
      int lane = i & 63, kb = (i>>6)&1, nt = (i>>7)&3, g = (i>>9)&3, p = (i>>11)&1;
      int l15 = lane & 15, lg = lane >> 4;
      const float* W2g = (p ? m2b_w : m1b_w) + g*64*64;
      int c = nt*16 + l15;
      f16x8 h8, l8;
      #pragma unroll
      for (int j=0;j<8;j++){
        float w = W2g[(kb*32 + lg*8 + j)*64 + c];
        _Float16 hh = (_Float16)w;
        h8[j] = hh; l8[j] = (_Float16)(w - (float)hh);
      }
      g_w2hi[i] = h8; g_w2lo[i] = l8;
    } else if (i < 6144) {        // edge W1 (folded) frags, from LDS — 2048 entries
      int k2 = i - 4096;
      int lane = k2 & 63, nt = (k2>>6)&3, g = (k2>>8)&3, p = (k2>>10)&1;
      int l15 = lane & 15, lg = lane >> 4;
      const float* Wf = sfold + (p*NG+g)*12*64;
      int c = nt*16 + l15;
      f16x8 h8, l8;
      #pragma unroll
      for (int j=0;j<8;j++){
        int k = lg*8 + j;
        float w = (k < 12) ? Wf[k*64 + c] : 0.f;
        _Float16 hh = (_Float16)w;
        h8[j] = hh; l8[j] = (_Float16)(w - (float)hh);
      }
      g_w1hi[k2] = h8; g_w1lo[k2] = l8;
    } else if (i < 6656) {        // node nu1_w[64:] frags
      int k2 = i - 6144;
      int lane = k2 & 63, kb = (k2>>6)&1, nt = (k2>>7)&3;
      int l15 = lane & 15, lg = lane >> 4;
      int c = nt*16 + l15;
      f16x8 h8, l8;
      #pragma unroll
      for (int j=0;j<8;j++){
        float w = nu1_w[(64 + kb*32 + lg*8 + j)*64 + c];
        _Float16 hh = (_Float16)w;
        h8[j] = hh; l8[j] = (_Float16)(w - (float)hh);
      }
      g_wn1hi[k2] = h8; g_wn1lo[k2] = l8;
    } else if (i < 7168) {        // node nu2_w frags
      int k2 = i - 6656;
      int lane = k2 & 63, kb = (k2>>6)&1, nt = (k2>>7)&3;
      int l15 = lane & 15, lg = lane >> 4;
      int c = nt*16 + l15;
      f16x8 h8, l8;
      #pragma unroll
      for (int j=0;j<8;j++){
        float w = nu2_w[(kb*32 + lg*8 + j)*64 + c];
        _Float16 hh = (_Float16)w;
        h8[j] = hh; l8[j] = (_Float16)(w - (float)hh);
      }
      g_wn2hi[k2] = h8; g_wn2lo[k2] = l8;
    } else {                      // node p1_w frags (8 nt)
      int k2 = i - 7168;
      int lane = k2 & 63, kb = (k2>>6)&1, nt = (k2>>7)&7;
      int l15 = lane & 15, lg = lane >> 4;
      int c = nt*16 + l15;
      f16x8 h8, l8;
      #pragma unroll
      for (int j=0;j<8;j++){
        float w = p1_w[(kb*32 + lg*8 + j)*128 + c];
        _Float16 hh = (_Float16)w;
        h8[j] = hh; l8[j] = (_Float16)(w - (float)hh);
      }
      g_wp1hi[k2] = h8; g_wp1lo[k2] = l8;
    }
  }
}

// ---------------- edge kernel: 8 edges x 8 batches = 64 rows per block -------
__global__ __launch_bounds__(128) void k_edge(
    const float* __restrict__ sites, const float* __restrict__ bonds,
    const int* __restrict__ idx1, const int* __restrict__ idx2,
    const float* __restrict__ m1b_b, const float* __restrict__ m2b_b,
    const float* __restrict__ att1_w, const float* __restrict__ att1_b,
    const float* __restrict__ att2_w, const float* __restrict__ att2_b) {
  int g = blockIdx.y;
  int cnt = g_ecnt[g];
  int e8 = blockIdx.x * 8;
  if (e8 >= cnt) return;

  __shared__ __align__(16) float hA[64*64];
  __shared__ __align__(16) float fls[64*12];
  __shared__ int sidx[64];

  int t = threadIdx.x;
  int l = t & 63;
  int wv = t >> 6;
  int l15 = l & 15;
  int lg  = l >> 4;
  int swzR = l15 << 2;

  if (t < 64) {
    int r = t, ei = r>>3, b = r&7;
    int eslot = e8 + ei;
    bool valid = eslot < cnt;
    int e = g_elist[g*NE + (valid ? eslot : e8)];
    int i1 = idx1[e], i2 = idx2[e];
    float d = bonds[b*NE + e];
    fls[r*12+0] = sites[b*NNODE + i1];
    fls[r*12+1] = sites[b*NNODE + i2];
    sidx[r] = valid ? (e*NB + b)*64 : -1;
    #pragma unroll
    for (int c=0;c<10;c++){
      float dd = d - c*(10.f/9.f);
      fls[r*12+2+c] = __expf(-dd*dd);
    }
  }
  __syncthreads();

  // feature A-fragments (shared by both paths): row=l15, k=lg*8+j
  f16x8 fhi[2], flo[2];
  #pragma unroll
  for (int mt=0;mt<2;mt++){
    f16x8 h8, l8;
    #pragma unroll
    for (int j=0;j<8;j++){ h8[j]=(_Float16)0; l8[j]=(_Float16)0; }
    int R = wv*32 + mt*16 + l15;
    if (lg == 0){
      float4 f0 = *(const float4*)&fls[R*12];
      float4 f1 = *(const float4*)&fls[R*12+4];
      float v;
      v=f0.x; h8[0]=(_Float16)v; l8[0]=(_Float16)(v-(float)h8[0]);
      v=f0.y; h8[1]=(_Float16)v; l8[1]=(_Float16)(v-(float)h8[1]);
      v=f0.z; h8[2]=(_Float16)v; l8[2]=(_Float16)(v-(float)h8[2]);
      v=f0.w; h8[3]=(_Float16)v; l8[3]=(_Float16)(v-(float)h8[3]);
      v=f1.x; h8[4]=(_Float16)v; l8[4]=(_Float16)(v-(float)h8[4]);
      v=f1.y; h8[5]=(_Float16)v; l8[5]=(_Float16)(v-(float)h8[5]);
      v=f1.z; h8[6]=(_Float16)v; l8[6]=(_Float16)(v-(float)h8[6]);
      v=f1.w; h8[7]=(_Float16)v; l8[7]=(_Float16)(v-(float)h8[7]);
    } else if (lg == 1){
      float4 f2 = *(const float4*)&fls[R*12+8];
      float v;
      v=f2.x; h8[0]=(_Float16)v; l8[0]=(_Float16)(v-(float)h8[0]);
      v=f2.y; h8[1]=(_Float16)v; l8[1]=(_Float16)(v-(float)h8[1]);
      v=f2.z; h8[2]=(_Float16)v; l8[2]=(_Float16)(v-(float)h8[2]);
      v=f2.w; h8[3]=(_Float16)v; l8[3]=(_Float16)(v-(float)h8[3]);
    }
    fhi[mt]=h8; flo[mt]=l8;
  }

  float comb[2][4][4];
  #pragma unroll
  for (int mt=0;mt<2;mt++)
    #pragma unroll
    for (int nt=0;nt<4;nt++)
      #pragma unroll
      for (int r=0;r<4;r++) comb[mt][nt][r] = 0.f;

  #pragma unroll
  for (int p=0;p<2;p++){
    const float* b2g = (p ? m2b_b : m1b_b) + g*64;
    int pg = p*NG + g;

    // layer 1 via MFMA
    #pragma unroll
    for (int nt=0;nt<4;nt++){
      int b1 = (pg*4 + nt)*64 + l;
      f16x8 w1h = g_w1hi[b1], w1l = g_w1lo[b1];
      float bias = g_bc[pg*64 + nt*16 + l15];
      #pragma unroll
      for (int mt=0;mt<2;mt++){
        f32x4 a = {bias, bias, bias, bias};
        a = __builtin_amdgcn_mfma_f32_16x16x32_f16(fhi[mt], w1h, a, 0,0,0);
        a = __builtin_amdgcn_mfma_f32_16x16x32_f16(fhi[mt], w1l, a, 0,0,0);
        a = __builtin_amdgcn_mfma_f32_16x16x32_f16(flo[mt], w1h, a, 0,0,0);
        #pragma unroll
        for (int r=0;r<4;r++){
          int R = wv*32 + mt*16 + lg*4 + r;
          hA[R*64 + ((nt*16 + l15) ^ ((R&15)<<2))] = lrelu(a[r]);
        }
      }
    }

    // layer 2: read h back as split A-frags (wave-private rows, no barrier)
    f16x8 ahi[2][2], alo[2][2];
    #pragma unroll
    for (int mt=0;mt<2;mt++){
      int R = wv*32 + mt*16 + l15;
      #pragma unroll
      for (int kb=0;kb<2;kb++){
        int k0 = kb*32 + lg*8;
        const float4 f0 = *(const float4*)&hA[R*64 + ((k0    ) ^ swzR)];
        const float4 f1 = *(const float4*)&hA[R*64 + ((k0 + 4) ^ swzR)];
        f16x8 hi8, lo8;
        float v0;
        v0=f0.x; hi8[0]=(_Float16)v0; lo8[0]=(_Float16)(v0-(float)hi8[0]);
        v0=f0.y; hi8[1]=(_Float16)v0; lo8[1]=(_Float16)(v0-(float)hi8[1]);
        v0=f0.z; hi8[2]=(_Float16)v0; lo8[2]=(_Float16)(v0-(float)hi8[2]);
        v0=f0.w; hi8[3]=(_Float16)v0; lo8[3]=(_Float16)(v0-(float)hi8[3]);
        v0=f1.x; hi8[4]=(_Float16)v0; lo8[4]=(_Float16)(v0-(float)hi8[4]);
        v0=f1.y; hi8[5]=(_Float16)v0; lo8[5]=(_Float16)(v0-(float)hi8[5]);
        v0=f1.z; hi8[6]=(_Float16)v0; lo8[6]=(_Float16)(v0-(float)hi8[6]);
        v0=f1.w; hi8[7]=(_Float16)v0; lo8[7]=(_Float16)(v0-(float)hi8[7]);
        ahi[mt][kb]=hi8; alo[mt][kb]=lo8;
      }
    }
    f32x4 accp[2][4];
    #pragma unroll
    for (int nt=0;nt<4;nt++){
      int b2 = ((pg*4 + nt)*2)*64 + l;
      f16x8 bh0 = g_w2hi[b2],    bl0 = g_w2lo[b2];
      f16x8 bh1 = g_w2hi[b2+64], bl1 = g_w2lo[b2+64];
      float bias = b2g[nt*16 + l15];
      #pragma unroll
      for (int mt=0;mt<2;mt++){
        f32x4 acc = {bias, bias, bias, bias};
        acc = __builtin_amdgcn_mfma_f32_16x16x32_f16(ahi[mt][0], bh0, acc, 0,0,0);
        acc = __builtin_amdgcn_mfma_f32_16x16x32_f16(ahi[mt][1], bh1, acc, 0,0,0);
        acc = __builtin_amdgcn_mfma_f32_16x16x32_f16(ahi[mt][0], bl0, acc, 0,0,0);
        acc = __builtin_amdgcn_mfma_f32_16x16x32_f16(ahi[mt][1], bl1, acc, 0,0,0);
        acc = __builtin_amdgcn_mfma_f32_16x16x32_f16(alo[mt][0], bh0, acc, 0,0,0);
        acc = __builtin_amdgcn_mfma_f32_16x16x32_f16(alo[mt][1], bh1, acc, 0,0,0);
        accp[mt][nt] = acc;
      }
    }
    // per-path epilogue: leaky -> attention gate -> accumulate into comb
    float ab = p ? att2_b[0] : att1_b[0];
    const float* aw = p ? att2_w : att1_w;
    #pragma unroll
    for (int mt=0;mt<2;mt++){
      float o[4][4];
      float pa[4] = {0.f,0.f,0.f,0.f};
      #pragma unroll
      for (int nt=0;nt<4;nt++){
        float w = aw[nt*16 + l15];
        #pragma unroll
        for (int r=0;r<4;r++){
          float ov = lrelu(accp[mt][nt][r]);
          o[nt][r] = ov;
          pa[r] += ov * w;
        }
      }
      #pragma unroll
      for (int r=0;r<4;r++){
        float s = pa[r];
        s += __shfl_xor(s, 1, 64);
        s += __shfl_xor(s, 2, 64);
        s += __shfl_xor(s, 4, 64);
        s += __shfl_xor(s, 8, 64);
        float sg = 1.f/(1.f + __expf(-(s + ab)));
        #pragma unroll
        for (int nt=0;nt<4;nt++) comb[mt][nt][r] += sg * o[nt][r];
      }
    }
  }

  // store combined messages as fp16
  #pragma unroll
  for (int mt=0;mt<2;mt++){
    #pragma unroll
    for (int r=0;r<4;r++){
      int R = wv*32 + mt*16 + lg*4 + r;
      int sb = sidx[R];
      if (sb >= 0){
        #pragma unroll
        for (int nt=0;nt<4;nt++) g_em16[sb + nt*16 + l15] = (_Float16)comb[mt][nt][r];
      }
    }
  }
}

// ---------------- gather: CSR segment-reduce (fp16 reads), no atomics --------
__global__ __launch_bounds__(256) void k_gather() {
  int w = blockIdx.x*4 + (threadIdx.x >> 6);
  int lane = threadIdx.x & 63;
  int n = w >> 3, b = w & 7;
  int off = g_noff[n], deg = g_ncnt[n];
  float s0 = 0.f, s1 = 0.f;
  int i = 0;
  for (; i+2 <= deg; i += 2){
    int e0 = g_csr[off+i], e1 = g_csr[off+i+1];
    s0 += (float)g_em16[(size_t)(e0*NB + b)*64 + lane];
    s1 += (float)g_em16[(size_t)(e1*NB + b)*64 + lane];
  }
  if (i < deg){
    int e0 = g_csr[off+i];
    s0 += (float)g_em16[(size_t)(e0*NB + b)*64 + lane];
  }
  g_msg[(b*NNODE + n)*64 + lane] = s0 + s1;
}

// ---------------- node kernel: 64 nodes/block, 3 chained MFMA GEMMs ----------
__global__ __launch_bounds__(128) void k_node(
    const float* __restrict__ sites,
    const float* __restrict__ se_w, const float* __restrict__ se_b,
    const float* __restrict__ nu2_b, const float* __restrict__ p1_b) {
  __shared__ __align__(16) float hA[64*64];
  __shared__ float xs[64];
  int t = threadIdx.x;
  int l = t & 63;
  int wv = t >> 6;
  int l15 = l & 15;
  int lg  = l >> 4;
  int swzR = l15 << 2;
  int b = blockIdx.x >> 5;
  int nbase = (blockIdx.x & 31) * 64;
  int wb = wv*32;

  if (t < 64) xs[t] = sites[b*NNODE + nbase + t];
  __syncthreads();

  // GEMM1 A-frags straight from g_msg: row=l15, k=kb*32+lg*8+j
  f16x8 ahi[2][2], alo[2][2];
  #pragma unroll
  for (int mt=0;mt<2;mt++){
    int row = b*NNODE + nbase + wb + mt*16 + l15;
    #pragma unroll
    for (int kb=0;kb<2;kb++){
      int k0 = kb*32 + lg*8;
      const float4 f0 = *(const float4*)&g_msg[row*64 + k0];
      const float4 f1 = *(const float4*)&g_msg[row*64 + k0 + 4];
      f16x8 hi8, lo8;
      float v0;
      v0=f0.x; hi8[0]=(_Float16)v0; lo8[0]=(_Float16)(v0-(float)hi8[0]);
      v0=f0.y; hi8[1]=(_Float16)v0; lo8[1]=(_Float16)(v0-(float)hi8[1]);
      v0=f0.z; hi8[2]=(_Float16)v0; lo8[2]=(_Float16)(v0-(float)hi8[2]);
      v0=f0.w; hi8[3]=(_Float16)v0; lo8[3]=(_Float16)(v0-(float)hi8[3]);
      v0=f1.x; hi8[4]=(_Float16)v0; lo8[4]=(_Float16)(v0-(float)hi8[4]);
      v0=f1.y; hi8[5]=(_Float16)v0; lo8[5]=(_Float16)(v0-(float)hi8[5]);
      v0=f1.z; hi8[6]=(_Float16)v0; lo8[6]=(_Float16)(v0-(float)hi8[6]);
      v0=f1.w; hi8[7]=(_Float16)v0; lo8[7]=(_Float16)(v0-(float)hi8[7]);
      ahi[mt][kb]=hi8; alo[mt][kb]=lo8;
    }
  }

  // GEMM1: h1 = lrelu(x*q1 + msg @ nu1_w[64:] + b1f) -> swizzled LDS
  #pragma unroll
  for (int nt=0;nt<4;nt++){
    f16x8 wh0 = g_wn1hi[(nt*2+0)*64 + l], wl0 = g_wn1lo[(nt*2+0)*64 + l];
    f16x8 wh1 = g_wn1hi[(nt*2+1)*64 + l], wl1 = g_wn1lo[(nt*2+1)*64 + l];
    int c = nt*16 + l15;
    float q = g_q1[c], bf = g_b1f[c];
    #pragma unroll
    for (int mt=0;mt<2;mt++){
      f32x4 a;
      #pragma unroll
      for (int r=0;r<4;r++){ int R = wb + mt*16 + lg*4 + r; a[r] = xs[R]*q + bf; }
      a = __builtin_amdgcn_mfma_f32_16x16x32_f16(ahi[mt][0], wh0, a, 0,0,0);
      a = __builtin_amdgcn_mfma_f32_16x16x32_f16(ahi[mt][1], wh1, a, 0,0,0);
      a = __builtin_amdgcn_mfma_f32_16x16x32_f16(ahi[mt][0], wl0, a, 0,0,0);
      a = __builtin_amdgcn_mfma_f32_16x16x32_f16(ahi[mt][1], wl1, a, 0,0,0);
      a = __builtin_amdgcn_mfma_f32_16x16x32_f16(alo[mt][0], wh0, a, 0,0,0);
      a = __builtin_amdgcn_mfma_f32_16x16x32_f16(alo[mt][1], wh1, a, 0,0,0);
      #pragma unroll
      for (int r=0;r<4;r++){
        int R = wb + mt*16 + lg*4 + r;
        hA[R*64 + (c ^ ((R&15)<<2))] = lrelu(a[r]);
      }
    }
  }

  // read h1 back (wave-private)
  #pragma unroll
  for (int mt=0;mt<2;mt++){
    int R = wb + mt*16 + l15;
    #pragma unroll
    for (int kb=0;kb<2;kb++){
      int k0 = kb*32 + lg*8;
      const float4 f0 = *(const float4*)&hA[R*64 + ((k0    ) ^ swzR)];
      const float4 f1 = *(const float4*)&hA[R*64 + ((k0 + 4) ^ swzR)];
      f16x8 hi8, lo8;
      float v0;
      v0=f0.x; hi8[0]=(_Float16)v0; lo8[0]=(_Float16)(v0-(float)hi8[0]);
      v0=f0.y; hi8[1]=(_Float16)v0; lo8[1]=(_Float16)(v0-(float)hi8[1]);
      v0=f0.z; hi8[2]=(_Float16)v0; lo8[2]=(_Float16)(v0-(float)hi8[2]);
      v0=f0.w; hi8[3]=(_Float16)v0; lo8[3]=(_Float16)(v0-(float)hi8[3]);
      v0=f1.x; hi8[4]=(_Float16)v0; lo8[4]=(_Float16)(v0-(float)hi8[4]);
      v0=f1.y; hi8[5]=(_Float16)v0; lo8[5]=(_Float16)(v0-(float)hi8[5]);
      v0=f1.z; hi8[6]=(_Float16)v0; lo8[6]=(_Float16)(v0-(float)hi8[6]);
      v0=f1.w; hi8[7]=(_Float16)v0; lo8[7]=(_Float16)(v0-(float)hi8[7]);
      ahi[mt][kb]=hi8; alo[mt][kb]=lo8;
    }
  }

  // GEMM2: s_new = x*se_w + se_b + lrelu(h1 @ nu2_w + nu2_b) -> swizzled LDS
  #pragma unroll
  for (int nt=0;nt<4;nt++){
    f16x8 wh0 = g_wn2hi[(nt*2+0)*64 + l], wl0 = g_wn2lo[(nt*2+0)*64 + l];
    f16x8 wh1 = g_wn2hi[(nt*2+1)*64 + l], wl1 = g_wn2lo[(nt*2+1)*64 + l];
    int c = nt*16 + l15;
    float b2 = nu2_b[c], sw = se_w[c], sb2 = se_b[c];
    #pragma unroll
    for (int mt=0;mt<2;mt++){
      f32x4 a = {b2, b2, b2, b2};
      a = __builtin_amdgcn_mfma_f32_16x16x32_f16(ahi[mt][0], wh0, a, 0,0,0);
      a = __builtin_amdgcn_mfma_f32_16x16x32_f16(ahi[mt][1], wh1, a, 0,0,0);
      a = __builtin_amdgcn_mfma_f32_16x16x32_f16(ahi[mt][0], wl0, a, 0,0,0);
      a = __builtin_amdgcn_mfma_f32_16x16x32_f16(ahi[mt][1], wl1, a, 0,0,0);
      a = __builtin_amdgcn_mfma_f32_16x16x32_f16(alo[mt][0], wh0, a, 0,0,0);
      a = __builtin_amdgcn_mfma_f32_16x16x32_f16(alo[mt][1], wh1, a, 0,0,0);
      #pragma unroll
      for (int r=0;r<4;r++){
        int R = wb + mt*16 + lg*4 + r;
        hA[R*64 + (c ^ ((R&15)<<2))] = xs[R]*sw + sb2 + lrelu(a[r]);
      }
    }
  }

  // read s_new back (wave-private)
  #pragma unroll
  for (int mt=0;mt<2;mt++){
    int R = wb + mt*16 + l15;
    #pragma unroll
    for (int kb=0;kb<2;kb++){
      int k0 = kb*32 + lg*8;
      const float4 f0 = *(const float4*)&hA[R*64 + ((k0    ) ^ swzR)];
      const float4 f1 = *(const float4*)&hA[R*64 + ((k0 + 4) ^ swzR)];
      f16x8 hi8, lo8;
      float v0;
      v0=f0.x; hi8[0]=(_Float16)v0; lo8[0]=(_Float16)(v0-(float)hi8[0]);
      v0=f0.y; hi8[1]=(_Float16)v0; lo8[1]=(_Float16)(v0-(float)hi8[1]);
      v0=f0.z; hi8[2]=(_Float16)v0; lo8[2]=(_Float16)(v0-(float)hi8[2]);
      v0=f0.w; hi8[3]=(_Float16)v0; lo8[3]=(_Float16)(v0-(float)hi8[3]);
      v0=f1.x; hi8[4]=(_Float16)v0; lo8[4]=(_Float16)(v0-(float)hi8[4]);
      v0=f1.y; hi8[5]=(_Float16)v0; lo8[5]=(_Float16)(v0-(float)hi8[5]);
      v0=f1.z; hi8[6]=(_Float16)v0; lo8[6]=(_Float16)(v0-(float)hi8[6]);
      v0=f1.w; hi8[7]=(_Float16)v0; lo8[7]=(_Float16)(v0-(float)hi8[7]);
      ahi[mt][kb]=hi8; alo[mt][kb]=lo8;
    }
  }

  // GEMM3: p = lrelu(s_new @ p1_w + p1_b); column-sum over rows -> g_psum
  #pragma unroll
  for (int nt=0;nt<8;nt++){
    f16x8 wh0 = g_wp1hi[(nt*2+0)*64 + l], wl0 = g_wp1lo[(nt*2+0)*64 + l];
    f16x8 wh1 = g_wp1hi[(nt*2+1)*64 + l], wl1 = g_wp1lo[(nt*2+1)*64 + l];
    int c = nt*16 + l15;
    float pb = p1_b[c];
    float colacc = 0.f;
    #pragma unroll
    for (int mt=0;mt<2;mt++){
      f32x4 a = {pb, pb, pb, pb};
      a = __builtin_amdgcn_mfma_f32_16x16x32_f16(ahi[mt][0], wh0, a, 0,0,0);
      a = __builtin_amdgcn_mfma_f32_16x16x32_f16(ahi[mt][1], wh1, a, 0,0,0);
      a = __builtin_amdgcn_mfma_f32_16x16x32_f16(ahi[mt][0], wl0, a, 0,0,0);
      a = __builtin_amdgcn_mfma_f32_16x16x32_f16(ahi[mt][1], wl1, a, 0,0,0);
      a = __builtin_amdgcn_mfma_f32_16x16x32_f16(alo[mt][0], wh0, a, 0,0,0);
      a = __builtin_amdgcn_mfma_f32_16x16x32_f16(alo[mt][1], wh1, a, 0,0,0);
      #pragma unroll
      for (int r=0;r<4;r++) colacc += lrelu(a[r]);
    }
    colacc += __shfl_xor(colacc, 16, 64);
    colacc += __shfl_xor(colacc, 32, 64);
    if (lg == 0) atomicAdd(&g_psum[b*NMLP + c], colacc);
  }
}

// ---------------- head: mean over nodes + final linear -----------------------
__global__ void k_head(const float* __restrict__ p2_w, const float* __restrict__ p2_b,
                       float* __restrict__ out) {
  int t = threadIdx.x; // 64 threads: 8 batches x 8 lanes
  int b = t >> 3, l = t & 7;
  float s = 0.f;
  for (int c=l;c<NMLP;c+=8) s += g_psum[b*NMLP + c] * p2_w[c];
  s += __shfl_xor(s, 1, 64);
  s += __shfl_xor(s, 2, 64);
  s += __shfl_xor(s, 4, 64);
  if (l == 0) out[b] = s * (1.f/(float)NNODE) + p2_b[0];
}

extern "C" void kernel_launch(void* const* d_in, const int* in_sizes, int n_in,
                              void* d_out, int out_size, void* d_ws, size_t ws_size,
                              hipStream_t stream) {
  (void)in_sizes; (void)n_in; (void)out_size; (void)d_ws; (void)ws_size;
  const float* sites = (const float*)d_in[0];
  const float* bonds = (const float*)d_in[1];
  const int*   idx1  = (const int*)d_in[2];
  const int*   idx2  = (const int*)d_in[3];
  const int*   uc    = (const int*)d_in[4];
  const float* se_w  = (const float*)d_in[5];
  const float* se_b  = (const float*)d_in[6];
  const float* ee_w  = (const float*)d_in[7];
  const float* ee_b  = (const float*)d_in[8];
  const float* m1a_w = (const float*)d_in[9];
  const float* m1a_b = (const float*)d_in[10];
  const float* m1b_w = (const float*)d_in[11];
  const float* m1b_b = (const float*)d_in[12];
  const float* m2a_w = (const float*)d_in[13];
  const float* m2a_b = (const float*)d_in[14];
  const float* m2b_w = (const float*)d_in[15];
  const float* m2b_b = (const float*)d_in[16];
  const float* att1_w = (const float*)d_in[17];
  const float* att1_b = (const float*)d_in[18];
  const float* att2_w = (const float*)d_in[19];
  const float* att2_b = (const float*)d_in[20];
  const float* nu1_w = (const float*)d_in[21];
  const float* nu1_b = (const float*)d_in[22];
  const float* nu2_w = (const float*)d_in[23];
  const float* nu2_b = (const float*)d_in[24];
  const float* p1_w  = (const float*)d_in[25];
  const float* p1_b  = (const float*)d_in[26];
  const float* p2_w  = (const float*)d_in[27];
  const float* p2_b  = (const float*)d_in[28];

  k_init<<<8, 256, 0, stream>>>();
  k_bucket<<<NE/256, 256, 0, stream>>>(uc, idx2);
  k_scan<<<1, 64, 0, stream>>>();
  k_place<<<NE/256, 256, 0, stream>>>(idx2);
  k_foldall<<<1, 1024, 0, stream>>>(se_w, se_b, ee_w, ee_b,
                                    m1a_w, m1a_b, m2a_w, m2a_b, nu1_w, nu1_b,
                                    m1b_w, m2b_w, nu2_w, p1_w);
  dim3 ge(NE/8, NG);
  k_edge<<<ge, 128, 0, stream>>>(sites, bonds, idx1, idx2,
                                 m1b_b, m2b_b,
                                 att1_w, att1_b, att2_w, att2_b);
  k_gather<<<(NNODE*NB)/4, 256, 0, stream>>>();
  k_node<<<NB*32, 128, 0, stream>>>(sites, se_w, se_b, nu2_b, p1_b);
  k_head<<<1, 64, 0, stream>>>(p2_w, p2_b, (float*)d_out);
}